// Round 16
// baseline (519.872 us; speedup 1.0000x reference)
//
#include <hip/hip_runtime.h>
#include <hip/hip_bf16.h>
#include <cstdint>

#define N_TOK   4096
#define D_MODEL 1024
#define N_HEAD  16
#define DH      64
#define INNER   2816

typedef __attribute__((ext_vector_type(8))) short bf16x8;
typedef __attribute__((ext_vector_type(4))) float f32x4;
typedef __attribute__((ext_vector_type(8))) unsigned short us8v;
typedef __attribute__((ext_vector_type(4))) unsigned short us4v;

union BF16x8U { bf16x8 v; uint32_t u[4]; };

__device__ __forceinline__ unsigned short f2bf(float x) {
    union { __hip_bfloat16 h; unsigned short u; } c;
    c.h = __float2bfloat16(x);
    return c.u;
}

__device__ __forceinline__ float bf2f(unsigned short u) {
    union { float f; uint32_t i; } c;
    c.i = ((uint32_t)u) << 16;
    return c.f;
}

__device__ __forceinline__ float silu_f(float x) {
    return x / (1.f + __expf(-x));
}

// async global->LDS, 16B per lane; LDS dest = wave-uniform base + lane*16
__device__ __forceinline__ void gld16(const unsigned short* g, unsigned short* l) {
    __builtin_amdgcn_global_load_lds(
        (const __attribute__((address_space(1))) void*)g,
        (__attribute__((address_space(3))) void*)l, 16, 0, 0);
}

// ---------------------------------------------------------------------------
// fp32 -> bf16 elementwise convert (8 elems/thread)
// ---------------------------------------------------------------------------
__global__ __launch_bounds__(256) void cvt_bf16(
    const float* __restrict__ in, unsigned short* __restrict__ out) {
    const size_t i8 = ((size_t)blockIdx.x * 256 + threadIdx.x) * 8;
    float4 a = *reinterpret_cast<const float4*>(&in[i8]);
    float4 b = *reinterpret_cast<const float4*>(&in[i8 + 4]);
    us8v o;
    o[0] = f2bf(a.x); o[1] = f2bf(a.y); o[2] = f2bf(a.z); o[3] = f2bf(a.w);
    o[4] = f2bf(b.x); o[5] = f2bf(b.y); o[6] = f2bf(b.z); o[7] = f2bf(b.w);
    *reinterpret_cast<us8v*>(&out[i8]) = o;
}

// ---------------------------------------------------------------------------
// W[K][N] fp32 -> WT[N][K] bf16, 64x64 LDS tile transpose. grid (N/64, K/64)
// ---------------------------------------------------------------------------
__global__ __launch_bounds__(256) void transpose_bf16(
    const float* __restrict__ W, unsigned short* __restrict__ WT,
    int K, int N) {
    __shared__ unsigned short T[64][65];
    const int n0 = blockIdx.x * 64;
    const int k0 = blockIdx.y * 64;
    const int t = threadIdx.x;
#pragma unroll
    for (int i = 0; i < 4; ++i) {
        const int id = i * 256 + t;
        const int r = id >> 4;
        const int c = (id & 15) * 4;
        float4 v = *reinterpret_cast<const float4*>(
            &W[(size_t)(k0 + r) * N + n0 + c]);
        T[c + 0][r] = f2bf(v.x);
        T[c + 1][r] = f2bf(v.y);
        T[c + 2][r] = f2bf(v.z);
        T[c + 3][r] = f2bf(v.w);
    }
    __syncthreads();
#pragma unroll
    for (int i = 0; i < 2; ++i) {
        const int id = i * 256 + t;
        const int n = id >> 3;
        const int c = (id & 7) * 8;
        us8v o;
#pragma unroll
        for (int j = 0; j < 8; ++j) o[j] = T[n][c + j];
        *reinterpret_cast<us8v*>(&WT[(size_t)(n0 + n) * K + k0 + c]) = o;
    }
}

// ---------------------------------------------------------------------------
// bf16 MFMA GEMM (m97 structure): C = A @ Bt^T over K columns starting at
// blockIdx.z*K (row stride lda). Partial C for slice z goes to Cout + z*M*N.
// 128x128 tile, BK=64, 4 waves, 16x16x32 MFMA, gload_lds w16, linear LDS.
// grid (N/128, M/128, nsplit). K % 64 == 0.
// ---------------------------------------------------------------------------
template<int OBF>
__global__ __launch_bounds__(256) void gemm_bf16(
    const unsigned short* __restrict__ A, const unsigned short* __restrict__ Bt,
    void* __restrict__ Cout, int M, int N, int K, int lda) {
    __shared__ unsigned short As[128 * 64];
    __shared__ unsigned short Bs[128 * 64];
    const int tid = threadIdx.x;
    const int lane = tid & 63;
    const int w = tid >> 6;
    const int l15 = lane & 15, lg = lane >> 4;
    const int wm = w >> 1, wn = w & 1;
    const int rowBase = blockIdx.y * 128;
    const int colBase = blockIdx.x * 128;
    const size_t koff = (size_t)blockIdx.z * K;

    const int srow = w * 32 + (lane >> 3);
    const int scol = (lane & 7) * 8;
    const unsigned short* Ag = &A[(size_t)(rowBase + srow) * lda + koff + scol];
    const unsigned short* Bg = &Bt[(size_t)(colBase + srow) * lda + koff + scol];

    f32x4 acc[4][4];
#pragma unroll
    for (int i = 0; i < 4; ++i)
#pragma unroll
        for (int j = 0; j < 4; ++j) acc[i][j] = (f32x4){0.f, 0.f, 0.f, 0.f};

    for (int k0 = 0; k0 < K; k0 += 64) {
#pragma unroll
        for (int j = 0; j < 4; ++j) {
            gld16(Ag + (size_t)j * 8 * lda + k0, &As[(w * 32 + j * 8) * 64]);
            gld16(Bg + (size_t)j * 8 * lda + k0, &Bs[(w * 32 + j * 8) * 64]);
        }
        __syncthreads();
        bf16x8 af[2][4], bfr[2][4];
#pragma unroll
        for (int kk = 0; kk < 2; ++kk) {
#pragma unroll
            for (int f = 0; f < 4; ++f) {
                af[kk][f] = *reinterpret_cast<const bf16x8*>(
                    &As[(wm * 64 + f * 16 + l15) * 64 + kk * 32 + lg * 8]);
                bfr[kk][f] = *reinterpret_cast<const bf16x8*>(
                    &Bs[(wn * 64 + f * 16 + l15) * 64 + kk * 32 + lg * 8]);
            }
        }
#pragma unroll
        for (int kk = 0; kk < 2; ++kk)
#pragma unroll
            for (int mf = 0; mf < 4; ++mf)
#pragma unroll
                for (int nf = 0; nf < 4; ++nf)
                    acc[mf][nf] = __builtin_amdgcn_mfma_f32_16x16x32_bf16(
                        bfr[kk][nf], af[kk][mf], acc[mf][nf], 0, 0, 0);
        __syncthreads();
    }
#pragma unroll
    for (int mf = 0; mf < 4; ++mf) {
#pragma unroll
        for (int nf = 0; nf < 4; ++nf) {
            const size_t m = rowBase + wm * 64 + mf * 16 + l15;
            const size_t n = colBase + wn * 64 + nf * 16 + lg * 4;
            if (OBF) {
                us4v o;
                o[0] = f2bf(acc[mf][nf][0]); o[1] = f2bf(acc[mf][nf][1]);
                o[2] = f2bf(acc[mf][nf][2]); o[3] = f2bf(acc[mf][nf][3]);
                *reinterpret_cast<us4v*>(
                    &((unsigned short*)Cout)[(size_t)blockIdx.z * M * N + m * N + n]) = o;
            } else {
                float4 o;
                o.x = acc[mf][nf][0]; o.y = acc[mf][nf][1];
                o.z = acc[mf][nf][2]; o.w = acc[mf][nf][3];
                *reinterpret_cast<float4*>(
                    &((float*)Cout)[(size_t)blockIdx.z * M * N + m * N + n]) = o;
            }
        }
    }
}

// ---------------------------------------------------------------------------
// bf16 MFMA GEMM, 64x128 tile (for small-N GEMMs: 2 blocks/CU).
// ---------------------------------------------------------------------------
template<int OBF>
__global__ __launch_bounds__(256) void gemm_bf16_t64(
    const unsigned short* __restrict__ A, const unsigned short* __restrict__ Bt,
    void* __restrict__ Cout, int M, int N, int K) {
    __shared__ unsigned short As[64 * 64];
    __shared__ unsigned short Bs[128 * 64];
    const int tid = threadIdx.x;
    const int lane = tid & 63;
    const int w = tid >> 6;
    const int l15 = lane & 15, lg = lane >> 4;
    const int rowBase = blockIdx.y * 64;
    const int colBase = blockIdx.x * 128;

    const int srowA = w * 16 + (lane >> 3);
    const int srowB = w * 32 + (lane >> 3);
    const int scol = (lane & 7) * 8;
    const unsigned short* Ag = &A[(size_t)(rowBase + srowA) * K + scol];
    const unsigned short* Bg = &Bt[(size_t)(colBase + srowB) * K + scol];

    f32x4 acc[4][2];
#pragma unroll
    for (int i = 0; i < 4; ++i)
#pragma unroll
        for (int j = 0; j < 2; ++j) acc[i][j] = (f32x4){0.f, 0.f, 0.f, 0.f};

    for (int k0 = 0; k0 < K; k0 += 64) {
#pragma unroll
        for (int j = 0; j < 2; ++j)
            gld16(Ag + (size_t)j * 8 * K + k0, &As[(w * 16 + j * 8) * 64]);
#pragma unroll
        for (int j = 0; j < 4; ++j)
            gld16(Bg + (size_t)j * 8 * K + k0, &Bs[(w * 32 + j * 8) * 64]);
        __syncthreads();
        bf16x8 af[2][4], bfr[2][2];
#pragma unroll
        for (int kk = 0; kk < 2; ++kk) {
#pragma unroll
            for (int f = 0; f < 4; ++f)
                af[kk][f] = *reinterpret_cast<const bf16x8*>(
                    &As[(f * 16 + l15) * 64 + kk * 32 + lg * 8]);
#pragma unroll
            for (int f = 0; f < 2; ++f)
                bfr[kk][f] = *reinterpret_cast<const bf16x8*>(
                    &Bs[(w * 32 + f * 16 + l15) * 64 + kk * 32 + lg * 8]);
        }
#pragma unroll
        for (int kk = 0; kk < 2; ++kk)
#pragma unroll
            for (int mf = 0; mf < 4; ++mf)
#pragma unroll
                for (int nf = 0; nf < 2; ++nf)
                    acc[mf][nf] = __builtin_amdgcn_mfma_f32_16x16x32_bf16(
                        bfr[kk][nf], af[kk][mf], acc[mf][nf], 0, 0, 0);
        __syncthreads();
    }
#pragma unroll
    for (int mf = 0; mf < 4; ++mf) {
#pragma unroll
        for (int nf = 0; nf < 2; ++nf) {
            const size_t m = rowBase + mf * 16 + l15;
            const size_t n = colBase + w * 32 + nf * 16 + lg * 4;
            if (OBF) {
                us4v o;
                o[0] = f2bf(acc[mf][nf][0]); o[1] = f2bf(acc[mf][nf][1]);
                o[2] = f2bf(acc[mf][nf][2]); o[3] = f2bf(acc[mf][nf][3]);
                *reinterpret_cast<us4v*>(
                    &((unsigned short*)Cout)[m * N + n]) = o;
            } else {
                float4 o;
                o.x = acc[mf][nf][0]; o.y = acc[mf][nf][1];
                o.z = acc[mf][nf][2]; o.w = acc[mf][nf][3];
                *reinterpret_cast<float4*>(&((float*)Cout)[m * N + n]) = o;
            }
        }
    }
}

// ---------------------------------------------------------------------------
// RoPE + RMS-norm from bf16 qkv; emits Qb (PRE-SCALED by 1/8), Kb, Vt, Vb.
// ---------------------------------------------------------------------------
__global__ __launch_bounds__(256) void rope_norm2(
    const unsigned short* __restrict__ qkv, const float* __restrict__ cosb,
    const float* __restrict__ sinb, unsigned short* __restrict__ Qb,
    unsigned short* __restrict__ Kb, unsigned short* __restrict__ Vt,
    unsigned short* __restrict__ Vb) {
    const int h = blockIdx.y;
    const int n0 = blockIdx.x * 64;
    const int wv = threadIdx.x >> 6;
    const int lane = threadIdx.x & 63;
    __shared__ unsigned short Vs[64][66];
#pragma unroll 1
    for (int it = 0; it < 16; ++it) {
        const int tn = it * 4 + wv;
        const int n = n0 + tn;
        const unsigned short* base = qkv + (size_t)n * (3 * D_MODEL) + h * DH;
        float qv = bf2f(base[lane]);
        float kv = bf2f(base[D_MODEL + lane]);
        const float c = cosb[n * DH + lane];
        const float s = sinb[n * DH + lane];
        const float qp = __shfl(qv, lane ^ 32, 64);
        const float kp = __shfl(kv, lane ^ 32, 64);
        const float sgn = (lane < 32) ? -1.f : 1.f;
        qv = qv * c + sgn * qp * s;
        kv = kv * c + sgn * kp * s;
        float sq = qv * qv, sk = kv * kv;
#pragma unroll
        for (int off = 32; off > 0; off >>= 1) {
            sq += __shfl_xor(sq, off, 64);
            sk += __shfl_xor(sk, off, 64);
        }
        qv *= rsqrtf(sq * (1.f / DH) + 1e-5f) * 0.125f;  // fold dh^-0.5 into Q
        kv *= rsqrtf(sk * (1.f / DH) + 1e-5f);
        const size_t o = ((size_t)h * N_TOK + n) * DH + lane;
        Qb[o] = f2bf(qv);
        Kb[o] = f2bf(kv);
        Vb[o] = base[2 * D_MODEL + lane];
        Vs[tn][lane] = base[2 * D_MODEL + lane];
    }
    __syncthreads();
    const int d = threadIdx.x >> 2;
    const int c0 = (threadIdx.x & 3) * 16;
    us8v o0, o1;
#pragma unroll
    for (int i = 0; i < 8; ++i) o0[i] = Vs[c0 + i][d];
#pragma unroll
    for (int i = 0; i < 8; ++i) o1[i] = Vs[c0 + 8 + i][d];
    unsigned short* dst = Vt + ((size_t)h * DH + d) * N_TOK + n0 + c0;
    *reinterpret_cast<us8v*>(dst) = o0;
    *reinterpret_cast<us8v*>(dst + 8) = o1;
}

// ---------------------------------------------------------------------------
// MFMA linear attention v7: qs=2 (32-query blocks, grid 2048) frees 48 regs,
// which fund a kf double-buffer prefetch (R12 mechanism) WITHOUT spilling at
// the lb(256,2) 256-reg cap (~184 demand). Shfl K=32 PV (validated fastest).
// ---------------------------------------------------------------------------
__global__ __launch_bounds__(256, 2) void attn_mfma2(
    const unsigned short* __restrict__ Qb, const unsigned short* __restrict__ Kb,
    const unsigned short* __restrict__ Vt, const unsigned short* __restrict__ Vb,
    unsigned short* __restrict__ Mout) {
    const int B = blockIdx.x;                        // [0, 2048)
    const int h = ((B & 7) << 1) | ((B >> 3) & 1);   // 2 heads per XCD
    const int q0 = (B >> 4) * 32;
    const int lane = threadIdx.x & 63;
    const int wv = threadIdx.x >> 6;
    const int l15 = lane & 15, lg = lane >> 4;
    const unsigned short* Qh = Qb + (size_t)h * N_TOK * DH;
    const unsigned short* Kh = Kb + (size_t)h * N_TOK * DH;
    const unsigned short* Vth = Vt + (size_t)h * DH * N_TOK;

    bf16x8 qf[2][2];
#pragma unroll
    for (int qs = 0; qs < 2; ++qs) {
        const unsigned short* qp = Qh + (size_t)(q0 + qs * 16 + l15) * DH + lg * 8;
        qf[qs][0] = *reinterpret_cast<const bf16x8*>(qp);
        qf[qs][1] = *reinterpret_cast<const bf16x8*>(qp + 32);
    }

    f32x4 ct[2][4];   // [qsub][ds]
#pragma unroll
    for (int i = 0; i < 2; ++i)
#pragma unroll
        for (int j = 0; j < 4; ++j) ct[i][j] = (f32x4){0.f, 0.f, 0.f, 0.f};
    float dpart[2] = {0.f, 0.f};

    const int sA = l15 + ((lg & 1) << 5);
    const int sB = sA + 16;
    const bool hi = (lg & 2) != 0;

    // per-kt K fragment loader (8 x 16B)
    auto load_kf = [&](bf16x8 (&dst)[4][2], int ktv) {
        const unsigned short* kp =
            Kh + (size_t)((wv * 16 + ktv) * 64 + l15) * DH + lg * 8;
#pragma unroll
        for (int ks = 0; ks < 4; ++ks) {
            dst[ks][0] = *reinterpret_cast<const bf16x8*>(kp + ks * 16 * DH);
            dst[ks][1] = *reinterpret_cast<const bf16x8*>(kp + ks * 16 * DH + 32);
        }
    };

    // one kt step: prefetch kt+1's K into kfn, compute with kf
    auto body = [&](bf16x8 (&kf)[4][2], bf16x8 (&kfn)[4][2], int kt) {
        if (kt < 15) load_kf(kfn, kt + 1);
        const int k0 = (wv * 16 + kt) * 64;
        const unsigned short* vp = Vth + (size_t)l15 * N_TOK + k0 + lg * 8;
        bf16x8 vf[4][2];
#pragma unroll
        for (int ds = 0; ds < 4; ++ds) {
            vf[ds][0] = *reinterpret_cast<const bf16x8*>(vp + (size_t)ds * 16 * N_TOK);
            vf[ds][1] = *reinterpret_cast<const bf16x8*>(vp + (size_t)ds * 16 * N_TOK + 32);
        }
#pragma unroll
        for (int qs = 0; qs < 2; ++qs) {
            // S^T subtiles (Q pre-scaled by 1/8)
            f32x4 st[4];
            __builtin_amdgcn_s_setprio(1);
#pragma unroll
            for (int ks = 0; ks < 4; ++ks) {
                f32x4 z = (f32x4){0.f, 0.f, 0.f, 0.f};
                z = __builtin_amdgcn_mfma_f32_16x16x32_bf16(kf[ks][0], qf[qs][0], z, 0, 0, 0);
                st[ks] = __builtin_amdgcn_mfma_f32_16x16x32_bf16(kf[ks][1], qf[qs][1], z, 0, 0, 0);
            }
            __builtin_amdgcn_s_setprio(0);
            // W = (elu(s)+1)^2, per-lane denom partial, pack bf16 pairs
            uint32_t wpk[4][2];
#pragma unroll
            for (int ks = 0; ks < 4; ++ks) {
                float w4[4];
#pragma unroll
                for (int r = 0; r < 4; ++r) {
                    const float x = st[ks][r];
                    float e = fmaxf(x, 0.f) + __expf(fminf(x, 0.f));
                    e = e * e;
                    w4[r] = e;
                    dpart[qs] += e;
                }
                wpk[ks][0] = (uint32_t)f2bf(w4[0]) | ((uint32_t)f2bf(w4[1]) << 16);
                wpk[ks][1] = (uint32_t)f2bf(w4[2]) | ((uint32_t)f2bf(w4[3]) << 16);
            }
            // repack W^T C-frags -> PV B-operand (16 shfls)
#pragma unroll
            for (int kh = 0; kh < 2; ++kh) {
                const uint32_t a0 = (uint32_t)__shfl((int)wpk[2 * kh][0], sA, 64);
                const uint32_t a1 = (uint32_t)__shfl((int)wpk[2 * kh][1], sA, 64);
                const uint32_t a2 = (uint32_t)__shfl((int)wpk[2 * kh][0], sB, 64);
                const uint32_t a3 = (uint32_t)__shfl((int)wpk[2 * kh][1], sB, 64);
                const uint32_t b0 = (uint32_t)__shfl((int)wpk[2 * kh + 1][0], sA, 64);
                const uint32_t b1 = (uint32_t)__shfl((int)wpk[2 * kh + 1][1], sA, 64);
                const uint32_t b2 = (uint32_t)__shfl((int)wpk[2 * kh + 1][0], sB, 64);
                const uint32_t b3 = (uint32_t)__shfl((int)wpk[2 * kh + 1][1], sB, 64);
                BF16x8U bb;
                bb.u[0] = hi ? b0 : a0;
                bb.u[1] = hi ? b1 : a1;
                bb.u[2] = hi ? b2 : a2;
                bb.u[3] = hi ? b3 : a3;
                __builtin_amdgcn_s_setprio(1);
#pragma unroll
                for (int ds = 0; ds < 4; ++ds)
                    ct[qs][ds] = __builtin_amdgcn_mfma_f32_16x16x32_bf16(
                        vf[ds][kh], bb.v, ct[qs][ds], 0, 0, 0);
                __builtin_amdgcn_s_setprio(0);
            }
        }
    };

    bf16x8 kfA[4][2], kfB[4][2];
    load_kf(kfA, 0);
#pragma unroll 1
    for (int kt2 = 0; kt2 < 16; kt2 += 2) {
        body(kfA, kfB, kt2);
        body(kfB, kfA, kt2 + 1);
    }

    // ---- two-phase cross-wave reduction ----
    __shared__ float accs2[2][32][72];   // 18,432 B
    __shared__ float dens[4][32];        //     512 B
#pragma unroll
    for (int qs = 0; qs < 2; ++qs) {
        float dp = dpart[qs];
        dp += __shfl_xor(dp, 16, 64);
        dp += __shfl_xor(dp, 32, 64);
        if (lg == 0) dens[wv][qs * 16 + l15] = dp;
    }
    if (wv >= 2) {
#pragma unroll
        for (int qs = 0; qs < 2; ++qs)
#pragma unroll
            for (int ds = 0; ds < 4; ++ds)
                *reinterpret_cast<f32x4*>(
                    &accs2[wv - 2][qs * 16 + l15][ds * 16 + lg * 4]) = ct[qs][ds];
    }
    __syncthreads();
    if (wv < 2) {
#pragma unroll
        for (int qs = 0; qs < 2; ++qs)
#pragma unroll
            for (int ds = 0; ds < 4; ++ds)
                ct[qs][ds] += *reinterpret_cast<const f32x4*>(
                    &accs2[wv][qs * 16 + l15][ds * 16 + lg * 4]);
        if (wv == 1) {
#pragma unroll
            for (int qs = 0; qs < 2; ++qs)
#pragma unroll
                for (int ds = 0; ds < 4; ++ds)
                    *reinterpret_cast<f32x4*>(
                        &accs2[1][qs * 16 + l15][ds * 16 + lg * 4]) = ct[qs][ds];
        }
    }
    __syncthreads();
    if (wv == 0) {
#pragma unroll
        for (int qs = 0; qs < 2; ++qs) {
            const int q = qs * 16 + l15;
            const float dnq = 1.f /
                (dens[0][q] + dens[1][q] + dens[2][q] + dens[3][q] + 1e-6f);
            const unsigned short* Vrow = Vb + ((size_t)h * N_TOK + q0 + q) * DH;
            unsigned short* Mrow = Mout + (size_t)(q0 + q) * D_MODEL + h * DH;
#pragma unroll
            for (int ds = 0; ds < 4; ++ds) {
                const int d = ds * 16 + lg * 4;
                const f32x4 s1 = *reinterpret_cast<const f32x4*>(&accs2[1][q][d]);
                const us4v vv = *reinterpret_cast<const us4v*>(&Vrow[d]);
                us4v o;
#pragma unroll
                for (int r = 0; r < 4; ++r)
                    o[r] = f2bf((ct[qs][ds][r] + s1[r]) * dnq - bf2f(vv[r]));
                *reinterpret_cast<us4v*>(&Mrow[d]) = o;
            }
        }
    }
}

// ---------------------------------------------------------------------------
// O = rmsnorm(X + R); fp32 out always, bf16 out if WB.
// ---------------------------------------------------------------------------
template<int WB>
__global__ __launch_bounds__(256) void rms_resid2(
    const float* __restrict__ X, const float* __restrict__ R,
    float* __restrict__ O32, unsigned short* __restrict__ Obf) {
    const int row = blockIdx.x;
    const int tid = threadIdx.x;
    const float4 xv = reinterpret_cast<const float4*>(X + (size_t)row * D_MODEL)[tid];
    const float4 rv = reinterpret_cast<const float4*>(R + (size_t)row * D_MODEL)[tid];
    const float t0 = xv.x + rv.x, t1 = xv.y + rv.y, t2 = xv.z + rv.z, t3 = xv.w + rv.w;
    float ss = t0 * t0 + t1 * t1 + t2 * t2 + t3 * t3;
#pragma unroll
    for (int off = 32; off > 0; off >>= 1) ss += __shfl_xor(ss, off, 64);
    __shared__ float red[4];
    if ((tid & 63) == 0) red[tid >> 6] = ss;
    __syncthreads();
    const float tot = red[0] + red[1] + red[2] + red[3];
    const float rs = rsqrtf(tot * (1.f / D_MODEL) + 1e-5f);
    float4 o;
    o.x = t0 * rs; o.y = t1 * rs; o.z = t2 * rs; o.w = t3 * rs;
    reinterpret_cast<float4*>(O32 + (size_t)row * D_MODEL)[tid] = o;
    if (WB) {
        us4v ob;
        ob[0] = f2bf(o.x); ob[1] = f2bf(o.y); ob[2] = f2bf(o.z); ob[3] = f2bf(o.w);
        *reinterpret_cast<us4v*>(&Obf[(size_t)row * D_MODEL + tid * 4]) = ob;
    }
}

// O = rmsnorm(Xa + Xb + R)  (split-K partial sum folded in; fp32 out)
__global__ __launch_bounds__(256) void rms_resid3(
    const float* __restrict__ Xa, const float* __restrict__ Xb,
    const float* __restrict__ R, float* __restrict__ O32) {
    const int row = blockIdx.x;
    const int tid = threadIdx.x;
    const float4 av = reinterpret_cast<const float4*>(Xa + (size_t)row * D_MODEL)[tid];
    const float4 bv = reinterpret_cast<const float4*>(Xb + (size_t)row * D_MODEL)[tid];
    const float4 rv = reinterpret_cast<const float4*>(R + (size_t)row * D_MODEL)[tid];
    const float t0 = av.x + bv.x + rv.x, t1 = av.y + bv.y + rv.y;
    const float t2 = av.z + bv.z + rv.z, t3 = av.w + bv.w + rv.w;
    float ss = t0 * t0 + t1 * t1 + t2 * t2 + t3 * t3;
#pragma unroll
    for (int off = 32; off > 0; off >>= 1) ss += __shfl_xor(ss, off, 64);
    __shared__ float red[4];
    if ((tid & 63) == 0) red[tid >> 6] = ss;
    __syncthreads();
    const float tot = red[0] + red[1] + red[2] + red[3];
    const float rs = rsqrtf(tot * (1.f / D_MODEL) + 1e-5f);
    float4 o;
    o.x = t0 * rs; o.y = t1 * rs; o.z = t2 * rs; o.w = t3 * rs;
    reinterpret_cast<float4*>(O32 + (size_t)row * D_MODEL)[tid] = o;
}

// ---------------------------------------------------------------------------
// FUSED: Hc = silu(conv3(silu(G)*U) + bias); reads GU directly.
// ---------------------------------------------------------------------------
__global__ __launch_bounds__(256) void dwconv_fused(
    const unsigned short* __restrict__ GU, const float* __restrict__ W,
    const float* __restrict__ Bv, unsigned short* __restrict__ Hc) {
    const size_t idx = (size_t)blockIdx.x * 256 + threadIdx.x;
    const int c8 = (int)(idx % (INNER / 8)) * 8;
    const int n = (int)(idx / (INNER / 8));
    float a[8];
    {
        float4 b0 = *reinterpret_cast<const float4*>(&Bv[c8]);
        float4 b1 = *reinterpret_cast<const float4*>(&Bv[c8 + 4]);
        a[0] = b0.x; a[1] = b0.y; a[2] = b0.z; a[3] = b0.w;
        a[4] = b1.x; a[5] = b1.y; a[6] = b1.z; a[7] = b1.w;
    }
#pragma unroll
    for (int k = 0; k < 3; ++k) {
        const int nn = n + k - 1;
        if (nn >= 0 && nn < N_TOK) {
            const unsigned short* row = &GU[(size_t)nn * (2 * INNER)];
            us8v g = *reinterpret_cast<const us8v*>(&row[c8]);
            us8v u = *reinterpret_cast<const us8v*>(&row[INNER + c8]);
            float4 w0 = *reinterpret_cast<const float4*>(&W[(size_t)k * INNER + c8]);
            float4 w1 = *reinterpret_cast<const float4*>(&W[(size_t)k * INNER + c8 + 4]);
            const float wv[8] = {w0.x, w0.y, w0.z, w0.w, w1.x, w1.y, w1.z, w1.w};
#pragma unroll
            for (int j = 0; j < 8; ++j) {
                const float hf = silu_f(bf2f(g[j])) * bf2f(u[j]);
                a[j] += hf * wv[j];
            }
        }
    }
    us8v o;
#pragma unroll
    for (int j = 0; j < 8; ++j) o[j] = f2bf(silu_f(a[j]));
    *reinterpret_cast<us8v*>(&Hc[(size_t)n * INNER + c8]) = o;
}

extern "C" void kernel_launch(void* const* d_in, const int* in_sizes, int n_in,
                              void* d_out, int out_size, void* d_ws, size_t ws_size,
                              hipStream_t stream) {
    const float* Qin   = (const float*)d_in[0];
    const float* cosb  = (const float*)d_in[1];
    const float* sinb  = (const float*)d_in[2];
    const float* Wqkv  = (const float*)d_in[3];
    const float* Wo    = (const float*)d_in[4];
    const float* Wup   = (const float*)d_in[5];
    const float* convw = (const float*)d_in[6];
    const float* convb = (const float*)d_in[7];
    const float* Wdown = (const float*)d_in[8];
    float* out = (float*)d_out;
    float* ws  = (float*)d_ws;

    // ---- workspace layout (float-unit offsets; peak ~139 MB)
    unsigned short* WqkvT  = (unsigned short*)(ws);              // [3072][1024]
    unsigned short* WoT    = (unsigned short*)(ws + 1572864);    // [1024][1024]
    unsigned short* WupT   = (unsigned short*)(ws + 2097152);    // [5632][1024]
    unsigned short* WdownT = (unsigned short*)(ws + 4980736);    // [1024][2816]
    unsigned short* Qin_bf = (unsigned short*)(ws + 6422528);    // [4096][1024]
    unsigned short* mcat   = (unsigned short*)(ws + 6422528);    // reuse (after QKV GEMM)
    unsigned short* qkv_bf = (unsigned short*)(ws + 8519680);    // [4096][3072] bf16 (dead after rope)
    float*          wo32   = ws + 8519680;                       // reuse (after rope)
    unsigned short* GU     = (unsigned short*)(ws + 8519680);    // [4096][5632] (after rms5)
    float*          dn32   = ws + 8519680;                       // [2][4096][1024] (after conv; GU dead)
    unsigned short* Qb     = (unsigned short*)(ws + 21102592);
    unsigned short* Kb     = (unsigned short*)(ws + 23199744);
    unsigned short* Vt     = (unsigned short*)(ws + 25296896);
    unsigned short* Vb     = (unsigned short*)(ws + 27394048);
    unsigned short* Hc     = (unsigned short*)(ws + 21102592);   // [4096][2816] (after attn)
    float*          Qi32   = ws + 29491200;                      // [4096][1024]
    unsigned short* Qi_bf  = (unsigned short*)(ws + 33685504);   // [4096][1024]

    const dim3 blk(256);
    // 0. weight / input prep
    cvt_bf16<<<2048, blk, 0, stream>>>(Qin, Qin_bf);
    transpose_bf16<<<dim3(48, 16), blk, 0, stream>>>(Wqkv, WqkvT, 1024, 3072);
    transpose_bf16<<<dim3(16, 16), blk, 0, stream>>>(Wo, WoT, 1024, 1024);
    transpose_bf16<<<dim3(88, 16), blk, 0, stream>>>(Wup, WupT, 1024, 5632);
    transpose_bf16<<<dim3(16, 44), blk, 0, stream>>>(Wdown, WdownT, 2816, 1024);
    // 1. QKV projection (bf16 out — RoPE/RMS read bf16)
    gemm_bf16<1><<<dim3(24, 32), blk, 0, stream>>>(
        Qin_bf, WqkvT, qkv_bf, 4096, 3072, 1024, 1024);
    // 2. RoPE + RMS + transposes
    rope_norm2<<<dim3(64, 16), blk, 0, stream>>>(qkv_bf, cosb, sinb, Qb, Kb, Vt, Vb);
    // 3. attention -> m_concat (bf16); 2048 blocks, XCD-clustered decode
    attn_mfma2<<<2048, blk, 0, stream>>>(Qb, Kb, Vt, Vb, mcat);
    // 4. W_o projection (fp32 out) — 64x128 tile: 512 blocks = 2/CU
    gemm_bf16_t64<0><<<dim3(8, 64), blk, 0, stream>>>(
        mcat, WoT, wo32, 4096, 1024, 1024);
    // 5. Q_interact = rmsnorm(Q_in + wo_out) -> fp32 + bf16
    rms_resid2<1><<<4096, blk, 0, stream>>>(wo32, Qin, Qi32, Qi_bf);
    // 6. GU = Qi @ Wup (bf16 out)
    gemm_bf16<1><<<dim3(44, 32), blk, 0, stream>>>(
        Qi_bf, WupT, GU, 4096, 5632, 1024, 1024);
    // 7+8. fused silu-mul + depthwise conv + bias + silu -> Hc
    dwconv_fused<<<5632, blk, 0, stream>>>(GU, convw, convb, Hc);
    // 9. W_down projection, split-K=2 (128x128 tile, 512 blocks = 2/CU)
    gemm_bf16<0><<<dim3(8, 32, 2), blk, 0, stream>>>(
        Hc, WdownT, dn32, 4096, 1024, 1408, 2816);
    // 10. out = rmsnorm(Qi + dnA + dnB)
    rms_resid3<<<4096, blk, 0, stream>>>(dn32, dn32 + 4194304, Qi32, out);
}

// Round 17
// 417.482 us; speedup vs baseline: 1.2453x; 1.2453x over previous
//
#include <hip/hip_runtime.h>
#include <hip/hip_bf16.h>
#include <cstdint>

#define N_TOK   4096
#define D_MODEL 1024
#define N_HEAD  16
#define DH      64
#define INNER   2816

typedef __attribute__((ext_vector_type(8))) short bf16x8;
typedef __attribute__((ext_vector_type(4))) float f32x4;
typedef __attribute__((ext_vector_type(8))) unsigned short us8v;
typedef __attribute__((ext_vector_type(4))) unsigned short us4v;

union BF16x8U { bf16x8 v; uint32_t u[4]; };

__device__ __forceinline__ unsigned short f2bf(float x) {
    union { __hip_bfloat16 h; unsigned short u; } c;
    c.h = __float2bfloat16(x);
    return c.u;
}

__device__ __forceinline__ float bf2f(unsigned short u) {
    union { float f; uint32_t i; } c;
    c.i = ((uint32_t)u) << 16;
    return c.f;
}

// pack two f32 -> one u32 of 2 bf16 in a single VALU instruction (gfx950)
__device__ __forceinline__ uint32_t cvt_pk_bf16(float lo, float hi) {
    uint32_t r;
    asm("v_cvt_pk_bf16_f32 %0, %1, %2" : "=v"(r) : "v"(lo), "v"(hi));
    return r;
}

__device__ __forceinline__ float silu_f(float x) {
    return x / (1.f + __expf(-x));
}

// async global->LDS, 16B per lane; LDS dest = wave-uniform base + lane*16
__device__ __forceinline__ void gld16(const unsigned short* g, unsigned short* l) {
    __builtin_amdgcn_global_load_lds(
        (const __attribute__((address_space(1))) void*)g,
        (__attribute__((address_space(3))) void*)l, 16, 0, 0);
}

// ---------------------------------------------------------------------------
// fp32 -> bf16 elementwise convert (8 elems/thread)
// ---------------------------------------------------------------------------
__global__ __launch_bounds__(256) void cvt_bf16(
    const float* __restrict__ in, unsigned short* __restrict__ out) {
    const size_t i8 = ((size_t)blockIdx.x * 256 + threadIdx.x) * 8;
    float4 a = *reinterpret_cast<const float4*>(&in[i8]);
    float4 b = *reinterpret_cast<const float4*>(&in[i8 + 4]);
    us8v o;
    o[0] = f2bf(a.x); o[1] = f2bf(a.y); o[2] = f2bf(a.z); o[3] = f2bf(a.w);
    o[4] = f2bf(b.x); o[5] = f2bf(b.y); o[6] = f2bf(b.z); o[7] = f2bf(b.w);
    *reinterpret_cast<us8v*>(&out[i8]) = o;
}

// ---------------------------------------------------------------------------
// W[K][N] fp32 -> WT[N][K] bf16, 64x64 LDS tile transpose. grid (N/64, K/64)
// ---------------------------------------------------------------------------
__global__ __launch_bounds__(256) void transpose_bf16(
    const float* __restrict__ W, unsigned short* __restrict__ WT,
    int K, int N) {
    __shared__ unsigned short T[64][65];
    const int n0 = blockIdx.x * 64;
    const int k0 = blockIdx.y * 64;
    const int t = threadIdx.x;
#pragma unroll
    for (int i = 0; i < 4; ++i) {
        const int id = i * 256 + t;
        const int r = id >> 4;
        const int c = (id & 15) * 4;
        float4 v = *reinterpret_cast<const float4*>(
            &W[(size_t)(k0 + r) * N + n0 + c]);
        T[c + 0][r] = f2bf(v.x);
        T[c + 1][r] = f2bf(v.y);
        T[c + 2][r] = f2bf(v.z);
        T[c + 3][r] = f2bf(v.w);
    }
    __syncthreads();
#pragma unroll
    for (int i = 0; i < 2; ++i) {
        const int id = i * 256 + t;
        const int n = id >> 3;
        const int c = (id & 7) * 8;
        us8v o;
#pragma unroll
        for (int j = 0; j < 8; ++j) o[j] = T[n][c + j];
        *reinterpret_cast<us8v*>(&WT[(size_t)(n0 + n) * K + k0 + c]) = o;
    }
}

// ---------------------------------------------------------------------------
// bf16 MFMA GEMM (m97 structure): C = A @ Bt^T over K columns starting at
// blockIdx.z*K (row stride lda). 128x128 tile, BK=64, 4 waves.
// ---------------------------------------------------------------------------
template<int OBF>
__global__ __launch_bounds__(256) void gemm_bf16(
    const unsigned short* __restrict__ A, const unsigned short* __restrict__ Bt,
    void* __restrict__ Cout, int M, int N, int K, int lda) {
    __shared__ unsigned short As[128 * 64];
    __shared__ unsigned short Bs[128 * 64];
    const int tid = threadIdx.x;
    const int lane = tid & 63;
    const int w = tid >> 6;
    const int l15 = lane & 15, lg = lane >> 4;
    const int wm = w >> 1, wn = w & 1;
    const int rowBase = blockIdx.y * 128;
    const int colBase = blockIdx.x * 128;
    const size_t koff = (size_t)blockIdx.z * K;

    const int srow = w * 32 + (lane >> 3);
    const int scol = (lane & 7) * 8;
    const unsigned short* Ag = &A[(size_t)(rowBase + srow) * lda + koff + scol];
    const unsigned short* Bg = &Bt[(size_t)(colBase + srow) * lda + koff + scol];

    f32x4 acc[4][4];
#pragma unroll
    for (int i = 0; i < 4; ++i)
#pragma unroll
        for (int j = 0; j < 4; ++j) acc[i][j] = (f32x4){0.f, 0.f, 0.f, 0.f};

    for (int k0 = 0; k0 < K; k0 += 64) {
#pragma unroll
        for (int j = 0; j < 4; ++j) {
            gld16(Ag + (size_t)j * 8 * lda + k0, &As[(w * 32 + j * 8) * 64]);
            gld16(Bg + (size_t)j * 8 * lda + k0, &Bs[(w * 32 + j * 8) * 64]);
        }
        __syncthreads();
        bf16x8 af[2][4], bfr[2][4];
#pragma unroll
        for (int kk = 0; kk < 2; ++kk) {
#pragma unroll
            for (int f = 0; f < 4; ++f) {
                af[kk][f] = *reinterpret_cast<const bf16x8*>(
                    &As[(wm * 64 + f * 16 + l15) * 64 + kk * 32 + lg * 8]);
                bfr[kk][f] = *reinterpret_cast<const bf16x8*>(
                    &Bs[(wn * 64 + f * 16 + l15) * 64 + kk * 32 + lg * 8]);
            }
        }
#pragma unroll
        for (int kk = 0; kk < 2; ++kk)
#pragma unroll
            for (int mf = 0; mf < 4; ++mf)
#pragma unroll
                for (int nf = 0; nf < 4; ++nf)
                    acc[mf][nf] = __builtin_amdgcn_mfma_f32_16x16x32_bf16(
                        bfr[kk][nf], af[kk][mf], acc[mf][nf], 0, 0, 0);
        __syncthreads();
    }
#pragma unroll
    for (int mf = 0; mf < 4; ++mf) {
#pragma unroll
        for (int nf = 0; nf < 4; ++nf) {
            const size_t m = rowBase + wm * 64 + mf * 16 + l15;
            const size_t n = colBase + wn * 64 + nf * 16 + lg * 4;
            if (OBF) {
                us4v o;
                o[0] = f2bf(acc[mf][nf][0]); o[1] = f2bf(acc[mf][nf][1]);
                o[2] = f2bf(acc[mf][nf][2]); o[3] = f2bf(acc[mf][nf][3]);
                *reinterpret_cast<us4v*>(
                    &((unsigned short*)Cout)[(size_t)blockIdx.z * M * N + m * N + n]) = o;
            } else {
                float4 o;
                o.x = acc[mf][nf][0]; o.y = acc[mf][nf][1];
                o.z = acc[mf][nf][2]; o.w = acc[mf][nf][3];
                *reinterpret_cast<float4*>(
                    &((float*)Cout)[(size_t)blockIdx.z * M * N + m * N + n]) = o;
            }
        }
    }
}

// ---------------------------------------------------------------------------
// bf16 MFMA GEMM, 64x128 tile (for small-N GEMMs: 2 blocks/CU).
// ---------------------------------------------------------------------------
template<int OBF>
__global__ __launch_bounds__(256) void gemm_bf16_t64(
    const unsigned short* __restrict__ A, const unsigned short* __restrict__ Bt,
    void* __restrict__ Cout, int M, int N, int K) {
    __shared__ unsigned short As[64 * 64];
    __shared__ unsigned short Bs[128 * 64];
    const int tid = threadIdx.x;
    const int lane = tid & 63;
    const int w = tid >> 6;
    const int l15 = lane & 15, lg = lane >> 4;
    const int rowBase = blockIdx.y * 64;
    const int colBase = blockIdx.x * 128;

    const int srowA = w * 16 + (lane >> 3);
    const int srowB = w * 32 + (lane >> 3);
    const int scol = (lane & 7) * 8;
    const unsigned short* Ag = &A[(size_t)(rowBase + srowA) * K + scol];
    const unsigned short* Bg = &Bt[(size_t)(colBase + srowB) * K + scol];

    f32x4 acc[4][2];
#pragma unroll
    for (int i = 0; i < 4; ++i)
#pragma unroll
        for (int j = 0; j < 2; ++j) acc[i][j] = (f32x4){0.f, 0.f, 0.f, 0.f};

    for (int k0 = 0; k0 < K; k0 += 64) {
#pragma unroll
        for (int j = 0; j < 2; ++j)
            gld16(Ag + (size_t)j * 8 * K + k0, &As[(w * 16 + j * 8) * 64]);
#pragma unroll
        for (int j = 0; j < 4; ++j)
            gld16(Bg + (size_t)j * 8 * K + k0, &Bs[(w * 32 + j * 8) * 64]);
        __syncthreads();
        bf16x8 af[2][4], bfr[2][2];
#pragma unroll
        for (int kk = 0; kk < 2; ++kk) {
#pragma unroll
            for (int f = 0; f < 4; ++f)
                af[kk][f] = *reinterpret_cast<const bf16x8*>(
                    &As[(f * 16 + l15) * 64 + kk * 32 + lg * 8]);
#pragma unroll
            for (int f = 0; f < 2; ++f)
                bfr[kk][f] = *reinterpret_cast<const bf16x8*>(
                    &Bs[(w * 32 + f * 16 + l15) * 64 + kk * 32 + lg * 8]);
        }
#pragma unroll
        for (int kk = 0; kk < 2; ++kk)
#pragma unroll
            for (int mf = 0; mf < 4; ++mf)
#pragma unroll
                for (int nf = 0; nf < 2; ++nf)
                    acc[mf][nf] = __builtin_amdgcn_mfma_f32_16x16x32_bf16(
                        bfr[kk][nf], af[kk][mf], acc[mf][nf], 0, 0, 0);
        __syncthreads();
    }
#pragma unroll
    for (int mf = 0; mf < 4; ++mf) {
#pragma unroll
        for (int nf = 0; nf < 2; ++nf) {
            const size_t m = rowBase + mf * 16 + l15;
            const size_t n = colBase + w * 32 + nf * 16 + lg * 4;
            if (OBF) {
                us4v o;
                o[0] = f2bf(acc[mf][nf][0]); o[1] = f2bf(acc[mf][nf][1]);
                o[2] = f2bf(acc[mf][nf][2]); o[3] = f2bf(acc[mf][nf][3]);
                *reinterpret_cast<us4v*>(
                    &((unsigned short*)Cout)[m * N + n]) = o;
            } else {
                float4 o;
                o.x = acc[mf][nf][0]; o.y = acc[mf][nf][1];
                o.z = acc[mf][nf][2]; o.w = acc[mf][nf][3];
                *reinterpret_cast<float4*>(&((float*)Cout)[m * N + n]) = o;
            }
        }
    }
}

// ---------------------------------------------------------------------------
// RoPE + RMS-norm from bf16 qkv; emits Qb (PRE-SCALED by 1/8), Kb, Vt, Vb.
// ---------------------------------------------------------------------------
__global__ __launch_bounds__(256) void rope_norm2(
    const unsigned short* __restrict__ qkv, const float* __restrict__ cosb,
    const float* __restrict__ sinb, unsigned short* __restrict__ Qb,
    unsigned short* __restrict__ Kb, unsigned short* __restrict__ Vt,
    unsigned short* __restrict__ Vb) {
    const int h = blockIdx.y;
    const int n0 = blockIdx.x * 64;
    const int wv = threadIdx.x >> 6;
    const int lane = threadIdx.x & 63;
    __shared__ unsigned short Vs[64][66];
#pragma unroll 1
    for (int it = 0; it < 16; ++it) {
        const int tn = it * 4 + wv;
        const int n = n0 + tn;
        const unsigned short* base = qkv + (size_t)n * (3 * D_MODEL) + h * DH;
        float qv = bf2f(base[lane]);
        float kv = bf2f(base[D_MODEL + lane]);
        const float c = cosb[n * DH + lane];
        const float s = sinb[n * DH + lane];
        const float qp = __shfl(qv, lane ^ 32, 64);
        const float kp = __shfl(kv, lane ^ 32, 64);
        const float sgn = (lane < 32) ? -1.f : 1.f;
        qv = qv * c + sgn * qp * s;
        kv = kv * c + sgn * kp * s;
        float sq = qv * qv, sk = kv * kv;
#pragma unroll
        for (int off = 32; off > 0; off >>= 1) {
            sq += __shfl_xor(sq, off, 64);
            sk += __shfl_xor(sk, off, 64);
        }
        qv *= rsqrtf(sq * (1.f / DH) + 1e-5f) * 0.125f;  // fold dh^-0.5 into Q
        kv *= rsqrtf(sk * (1.f / DH) + 1e-5f);
        const size_t o = ((size_t)h * N_TOK + n) * DH + lane;
        Qb[o] = f2bf(qv);
        Kb[o] = f2bf(kv);
        Vb[o] = base[2 * D_MODEL + lane];
        Vs[tn][lane] = base[2 * D_MODEL + lane];
    }
    __syncthreads();
    const int d = threadIdx.x >> 2;
    const int c0 = (threadIdx.x & 3) * 16;
    us8v o0, o1;
#pragma unroll
    for (int i = 0; i < 8; ++i) o0[i] = Vs[c0 + i][d];
#pragma unroll
    for (int i = 0; i < 8; ++i) o1[i] = Vs[c0 + 8 + i][d];
    unsigned short* dst = Vt + ((size_t)h * DH + d) * N_TOK + n0 + c0;
    *reinterpret_cast<us8v*>(dst) = o0;
    *reinterpret_cast<us8v*>(dst + 8) = o1;
}

// ---------------------------------------------------------------------------
// MFMA linear attention (R8-exact structure: qs=4, grid 1024, lb(256,2),
// shfl K=32 PV — 170 us 5x-confirmed) + v_cvt_pk_bf16_f32 pack (1 instr per
// f32 pair instead of ~8; zero register/structure delta).
// ---------------------------------------------------------------------------
__global__ __launch_bounds__(256, 2) void attn_mfma2(
    const unsigned short* __restrict__ Qb, const unsigned short* __restrict__ Kb,
    const unsigned short* __restrict__ Vt, const unsigned short* __restrict__ Vb,
    unsigned short* __restrict__ Mout) {
    const int B = blockIdx.x;
    const int h = ((B & 7) << 1) | ((B >> 3) & 1);   // 2 heads per XCD
    const int q0 = (B >> 4) * 64;
    const int lane = threadIdx.x & 63;
    const int wv = threadIdx.x >> 6;
    const int l15 = lane & 15, lg = lane >> 4;
    const unsigned short* Qh = Qb + (size_t)h * N_TOK * DH;
    const unsigned short* Kh = Kb + (size_t)h * N_TOK * DH;
    const unsigned short* Vth = Vt + (size_t)h * DH * N_TOK;

    bf16x8 qf[4][2];
#pragma unroll
    for (int qs = 0; qs < 4; ++qs) {
        const unsigned short* qp = Qh + (size_t)(q0 + qs * 16 + l15) * DH + lg * 8;
        qf[qs][0] = *reinterpret_cast<const bf16x8*>(qp);
        qf[qs][1] = *reinterpret_cast<const bf16x8*>(qp + 32);
    }

    f32x4 ct[4][4];   // [qsub][ds]
#pragma unroll
    for (int i = 0; i < 4; ++i)
#pragma unroll
        for (int j = 0; j < 4; ++j) ct[i][j] = (f32x4){0.f, 0.f, 0.f, 0.f};
    float dpart[4] = {0.f, 0.f, 0.f, 0.f};

    const int sA = l15 + ((lg & 1) << 5);
    const int sB = sA + 16;
    const bool hi = (lg & 2) != 0;

#pragma unroll 1
    for (int kt = 0; kt < 16; ++kt) {
        const int k0 = (wv * 16 + kt) * 64;
        const unsigned short* kp = Kh + (size_t)(k0 + l15) * DH + lg * 8;
        bf16x8 kf[4][2];
#pragma unroll
        for (int ks = 0; ks < 4; ++ks) {
            kf[ks][0] = *reinterpret_cast<const bf16x8*>(kp + ks * 16 * DH);
            kf[ks][1] = *reinterpret_cast<const bf16x8*>(kp + ks * 16 * DH + 32);
        }
        const unsigned short* vp = Vth + (size_t)l15 * N_TOK + k0 + lg * 8;
        bf16x8 vf[4][2];
#pragma unroll
        for (int ds = 0; ds < 4; ++ds) {
            vf[ds][0] = *reinterpret_cast<const bf16x8*>(vp + (size_t)ds * 16 * N_TOK);
            vf[ds][1] = *reinterpret_cast<const bf16x8*>(vp + (size_t)ds * 16 * N_TOK + 32);
        }
#pragma unroll
        for (int qs = 0; qs < 4; ++qs) {
            // S^T subtiles (Q pre-scaled by 1/8)
            f32x4 st[4];
            __builtin_amdgcn_s_setprio(1);
#pragma unroll
            for (int ks = 0; ks < 4; ++ks) {
                f32x4 z = (f32x4){0.f, 0.f, 0.f, 0.f};
                z = __builtin_amdgcn_mfma_f32_16x16x32_bf16(kf[ks][0], qf[qs][0], z, 0, 0, 0);
                st[ks] = __builtin_amdgcn_mfma_f32_16x16x32_bf16(kf[ks][1], qf[qs][1], z, 0, 0, 0);
            }
            __builtin_amdgcn_s_setprio(0);
            // W = (elu(s)+1)^2, per-lane denom partial, pack via v_cvt_pk
            uint32_t wpk[4][2];
#pragma unroll
            for (int ks = 0; ks < 4; ++ks) {
                float w4[4];
#pragma unroll
                for (int r = 0; r < 4; ++r) {
                    const float x = st[ks][r];
                    float e = fmaxf(x, 0.f) + __expf(fminf(x, 0.f));
                    e = e * e;
                    w4[r] = e;
                    dpart[qs] += e;
                }
                wpk[ks][0] = cvt_pk_bf16(w4[0], w4[1]);
                wpk[ks][1] = cvt_pk_bf16(w4[2], w4[3]);
            }
            // repack W^T C-frags -> PV B-operand (16 shfls)
#pragma unroll
            for (int kh = 0; kh < 2; ++kh) {
                const uint32_t a0 = (uint32_t)__shfl((int)wpk[2 * kh][0], sA, 64);
                const uint32_t a1 = (uint32_t)__shfl((int)wpk[2 * kh][1], sA, 64);
                const uint32_t a2 = (uint32_t)__shfl((int)wpk[2 * kh][0], sB, 64);
                const uint32_t a3 = (uint32_t)__shfl((int)wpk[2 * kh][1], sB, 64);
                const uint32_t b0 = (uint32_t)__shfl((int)wpk[2 * kh + 1][0], sA, 64);
                const uint32_t b1 = (uint32_t)__shfl((int)wpk[2 * kh + 1][1], sA, 64);
                const uint32_t b2 = (uint32_t)__shfl((int)wpk[2 * kh + 1][0], sB, 64);
                const uint32_t b3 = (uint32_t)__shfl((int)wpk[2 * kh + 1][1], sB, 64);
                BF16x8U bb;
                bb.u[0] = hi ? b0 : a0;
                bb.u[1] = hi ? b1 : a1;
                bb.u[2] = hi ? b2 : a2;
                bb.u[3] = hi ? b3 : a3;
                __builtin_amdgcn_s_setprio(1);
#pragma unroll
                for (int ds = 0; ds < 4; ++ds)
                    ct[qs][ds] = __builtin_amdgcn_mfma_f32_16x16x32_bf16(
                        vf[ds][kh], bb.v, ct[qs][ds], 0, 0, 0);
                __builtin_amdgcn_s_setprio(0);
            }
        }
    }

    // ---- two-phase cross-wave reduction ----
    __shared__ float accs2[2][64][72];   // 36,864 B
    __shared__ float dens[4][64];        //  1,024 B
#pragma unroll
    for (int qs = 0; qs < 4; ++qs) {
        float dp = dpart[qs];
        dp += __shfl_xor(dp, 16, 64);
        dp += __shfl_xor(dp, 32, 64);
        if (lg == 0) dens[wv][qs * 16 + l15] = dp;
    }
    if (wv >= 2) {
#pragma unroll
        for (int qs = 0; qs < 4; ++qs)
#pragma unroll
            for (int ds = 0; ds < 4; ++ds)
                *reinterpret_cast<f32x4*>(
                    &accs2[wv - 2][qs * 16 + l15][ds * 16 + lg * 4]) = ct[qs][ds];
    }
    __syncthreads();
    if (wv < 2) {
#pragma unroll
        for (int qs = 0; qs < 4; ++qs)
#pragma unroll
            for (int ds = 0; ds < 4; ++ds)
                ct[qs][ds] += *reinterpret_cast<const f32x4*>(
                    &accs2[wv][qs * 16 + l15][ds * 16 + lg * 4]);
        if (wv == 1) {
#pragma unroll
            for (int qs = 0; qs < 4; ++qs)
#pragma unroll
                for (int ds = 0; ds < 4; ++ds)
                    *reinterpret_cast<f32x4*>(
                        &accs2[1][qs * 16 + l15][ds * 16 + lg * 4]) = ct[qs][ds];
        }
    }
    __syncthreads();
    if (wv == 0) {
#pragma unroll
        for (int qs = 0; qs < 4; ++qs) {
            const int q = qs * 16 + l15;
            const float dnq = 1.f /
                (dens[0][q] + dens[1][q] + dens[2][q] + dens[3][q] + 1e-6f);
            const unsigned short* Vrow = Vb + ((size_t)h * N_TOK + q0 + q) * DH;
            unsigned short* Mrow = Mout + (size_t)(q0 + q) * D_MODEL + h * DH;
#pragma unroll
            for (int ds = 0; ds < 4; ++ds) {
                const int d = ds * 16 + lg * 4;
                const f32x4 s1 = *reinterpret_cast<const f32x4*>(&accs2[1][q][d]);
                const us4v vv = *reinterpret_cast<const us4v*>(&Vrow[d]);
                us4v o;
#pragma unroll
                for (int r = 0; r < 4; ++r)
                    o[r] = f2bf((ct[qs][ds][r] + s1[r]) * dnq - bf2f(vv[r]));
                *reinterpret_cast<us4v*>(&Mrow[d]) = o;
            }
        }
    }
}

// ---------------------------------------------------------------------------
// O = rmsnorm(X + R); fp32 out always, bf16 out if WB.
// ---------------------------------------------------------------------------
template<int WB>
__global__ __launch_bounds__(256) void rms_resid2(
    const float* __restrict__ X, const float* __restrict__ R,
    float* __restrict__ O32, unsigned short* __restrict__ Obf) {
    const int row = blockIdx.x;
    const int tid = threadIdx.x;
    const float4 xv = reinterpret_cast<const float4*>(X + (size_t)row * D_MODEL)[tid];
    const float4 rv = reinterpret_cast<const float4*>(R + (size_t)row * D_MODEL)[tid];
    const float t0 = xv.x + rv.x, t1 = xv.y + rv.y, t2 = xv.z + rv.z, t3 = xv.w + rv.w;
    float ss = t0 * t0 + t1 * t1 + t2 * t2 + t3 * t3;
#pragma unroll
    for (int off = 32; off > 0; off >>= 1) ss += __shfl_xor(ss, off, 64);
    __shared__ float red[4];
    if ((tid & 63) == 0) red[tid >> 6] = ss;
    __syncthreads();
    const float tot = red[0] + red[1] + red[2] + red[3];
    const float rs = rsqrtf(tot * (1.f / D_MODEL) + 1e-5f);
    float4 o;
    o.x = t0 * rs; o.y = t1 * rs; o.z = t2 * rs; o.w = t3 * rs;
    reinterpret_cast<float4*>(O32 + (size_t)row * D_MODEL)[tid] = o;
    if (WB) {
        us4v ob;
        ob[0] = f2bf(o.x); ob[1] = f2bf(o.y); ob[2] = f2bf(o.z); ob[3] = f2bf(o.w);
        *reinterpret_cast<us4v*>(&Obf[(size_t)row * D_MODEL + tid * 4]) = ob;
    }
}

// O = rmsnorm(Xa + Xb + R)  (split-K partial sum folded in; fp32 out)
__global__ __launch_bounds__(256) void rms_resid3(
    const float* __restrict__ Xa, const float* __restrict__ Xb,
    const float* __restrict__ R, float* __restrict__ O32) {
    const int row = blockIdx.x;
    const int tid = threadIdx.x;
    const float4 av = reinterpret_cast<const float4*>(Xa + (size_t)row * D_MODEL)[tid];
    const float4 bv = reinterpret_cast<const float4*>(Xb + (size_t)row * D_MODEL)[tid];
    const float4 rv = reinterpret_cast<const float4*>(R + (size_t)row * D_MODEL)[tid];
    const float t0 = av.x + bv.x + rv.x, t1 = av.y + bv.y + rv.y;
    const float t2 = av.z + bv.z + rv.z, t3 = av.w + bv.w + rv.w;
    float ss = t0 * t0 + t1 * t1 + t2 * t2 + t3 * t3;
#pragma unroll
    for (int off = 32; off > 0; off >>= 1) ss += __shfl_xor(ss, off, 64);
    __shared__ float red[4];
    if ((tid & 63) == 0) red[tid >> 6] = ss;
    __syncthreads();
    const float tot = red[0] + red[1] + red[2] + red[3];
    const float rs = rsqrtf(tot * (1.f / D_MODEL) + 1e-5f);
    float4 o;
    o.x = t0 * rs; o.y = t1 * rs; o.z = t2 * rs; o.w = t3 * rs;
    reinterpret_cast<float4*>(O32 + (size_t)row * D_MODEL)[tid] = o;
}

// ---------------------------------------------------------------------------
// FUSED: Hc = silu(conv3(silu(G)*U) + bias); reads GU directly.
// ---------------------------------------------------------------------------
__global__ __launch_bounds__(256) void dwconv_fused(
    const unsigned short* __restrict__ GU, const float* __restrict__ W,
    const float* __restrict__ Bv, unsigned short* __restrict__ Hc) {
    const size_t idx = (size_t)blockIdx.x * 256 + threadIdx.x;
    const int c8 = (int)(idx % (INNER / 8)) * 8;
    const int n = (int)(idx / (INNER / 8));
    float a[8];
    {
        float4 b0 = *reinterpret_cast<const float4*>(&Bv[c8]);
        float4 b1 = *reinterpret_cast<const float4*>(&Bv[c8 + 4]);
        a[0] = b0.x; a[1] = b0.y; a[2] = b0.z; a[3] = b0.w;
        a[4] = b1.x; a[5] = b1.y; a[6] = b1.z; a[7] = b1.w;
    }
#pragma unroll
    for (int k = 0; k < 3; ++k) {
        const int nn = n + k - 1;
        if (nn >= 0 && nn < N_TOK) {
            const unsigned short* row = &GU[(size_t)nn * (2 * INNER)];
            us8v g = *reinterpret_cast<const us8v*>(&row[c8]);
            us8v u = *reinterpret_cast<const us8v*>(&row[INNER + c8]);
            float4 w0 = *reinterpret_cast<const float4*>(&W[(size_t)k * INNER + c8]);
            float4 w1 = *reinterpret_cast<const float4*>(&W[(size_t)k * INNER + c8 + 4]);
            const float wv[8] = {w0.x, w0.y, w0.z, w0.w, w1.x, w1.y, w1.z, w1.w};
#pragma unroll
            for (int j = 0; j < 8; ++j) {
                const float hf = silu_f(bf2f(g[j])) * bf2f(u[j]);
                a[j] += hf * wv[j];
            }
        }
    }
    us8v o;
#pragma unroll
    for (int j = 0; j < 8; ++j) o[j] = f2bf(silu_f(a[j]));
    *reinterpret_cast<us8v*>(&Hc[(size_t)n * INNER + c8]) = o;
}

extern "C" void kernel_launch(void* const* d_in, const int* in_sizes, int n_in,
                              void* d_out, int out_size, void* d_ws, size_t ws_size,
                              hipStream_t stream) {
    const float* Qin   = (const float*)d_in[0];
    const float* cosb  = (const float*)d_in[1];
    const float* sinb  = (const float*)d_in[2];
    const float* Wqkv  = (const float*)d_in[3];
    const float* Wo    = (const float*)d_in[4];
    const float* Wup   = (const float*)d_in[5];
    const float* convw = (const float*)d_in[6];
    const float* convb = (const float*)d_in[7];
    const float* Wdown = (const float*)d_in[8];
    float* out = (float*)d_out;
    float* ws  = (float*)d_ws;

    // ---- workspace layout (float-unit offsets; peak ~139 MB)
    unsigned short* WqkvT  = (unsigned short*)(ws);              // [3072][1024]
    unsigned short* WoT    = (unsigned short*)(ws + 1572864);    // [1024][1024]
    unsigned short* WupT   = (unsigned short*)(ws + 2097152);    // [5632][1024]
    unsigned short* WdownT = (unsigned short*)(ws + 4980736);    // [1024][2816]
    unsigned short* Qin_bf = (unsigned short*)(ws + 6422528);    // [4096][1024]
    unsigned short* mcat   = (unsigned short*)(ws + 6422528);    // reuse (after QKV GEMM)
    unsigned short* qkv_bf = (unsigned short*)(ws + 8519680);    // [4096][3072] bf16 (dead after rope)
    float*          wo32   = ws + 8519680;                       // reuse (after rope)
    unsigned short* GU     = (unsigned short*)(ws + 8519680);    // [4096][5632] (after rms5)
    float*          dn32   = ws + 8519680;                       // [2][4096][1024] (after conv; GU dead)
    unsigned short* Qb     = (unsigned short*)(ws + 21102592);
    unsigned short* Kb     = (unsigned short*)(ws + 23199744);
    unsigned short* Vt     = (unsigned short*)(ws + 25296896);
    unsigned short* Vb     = (unsigned short*)(ws + 27394048);
    unsigned short* Hc     = (unsigned short*)(ws + 21102592);   // [4096][2816] (after attn)
    float*          Qi32   = ws + 29491200;                      // [4096][1024]
    unsigned short* Qi_bf  = (unsigned short*)(ws + 33685504);   // [4096][1024]

    const dim3 blk(256);
    // 0. weight / input prep
    cvt_bf16<<<2048, blk, 0, stream>>>(Qin, Qin_bf);
    transpose_bf16<<<dim3(48, 16), blk, 0, stream>>>(Wqkv, WqkvT, 1024, 3072);
    transpose_bf16<<<dim3(16, 16), blk, 0, stream>>>(Wo, WoT, 1024, 1024);
    transpose_bf16<<<dim3(88, 16), blk, 0, stream>>>(Wup, WupT, 1024, 5632);
    transpose_bf16<<<dim3(16, 44), blk, 0, stream>>>(Wdown, WdownT, 2816, 1024);
    // 1. QKV projection (bf16 out — RoPE/RMS read bf16)
    gemm_bf16<1><<<dim3(24, 32), blk, 0, stream>>>(
        Qin_bf, WqkvT, qkv_bf, 4096, 3072, 1024, 1024);
    // 2. RoPE + RMS + transposes
    rope_norm2<<<dim3(64, 16), blk, 0, stream>>>(qkv_bf, cosb, sinb, Qb, Kb, Vt, Vb);
    // 3. attention -> m_concat (bf16); 1024 blocks, XCD-clustered decode
    attn_mfma2<<<1024, blk, 0, stream>>>(Qb, Kb, Vt, Vb, mcat);
    // 4. W_o projection (fp32 out) — 64x128 tile: 512 blocks = 2/CU
    gemm_bf16_t64<0><<<dim3(8, 64), blk, 0, stream>>>(
        mcat, WoT, wo32, 4096, 1024, 1024);
    // 5. Q_interact = rmsnorm(Q_in + wo_out) -> fp32 + bf16
    rms_resid2<1><<<4096, blk, 0, stream>>>(wo32, Qin, Qi32, Qi_bf);
    // 6. GU = Qi @ Wup (bf16 out)
    gemm_bf16<1><<<dim3(44, 32), blk, 0, stream>>>(
        Qi_bf, WupT, GU, 4096, 5632, 1024, 1024);
    // 7+8. fused silu-mul + depthwise conv + bias + silu -> Hc
    dwconv_fused<<<5632, blk, 0, stream>>>(GU, convw, convb, Hc);
    // 9. W_down projection, split-K=2 (128x128 tile, 512 blocks = 2/CU)
    gemm_bf16<0><<<dim3(8, 32, 2), blk, 0, stream>>>(
        Hc, WdownT, dn32, 4096, 1024, 1408, 2816);
    // 10. out = rmsnorm(Qi + dnA + dnB)
    rms_resid3<<<4096, blk, 0, stream>>>(dn32, dn32 + 4194304, Qi32, out);
}

// Round 19
// 411.182 us; speedup vs baseline: 1.2643x; 1.0153x over previous
//
#include <hip/hip_runtime.h>
#include <hip/hip_bf16.h>
#include <cstdint>

#define N_TOK   4096
#define D_MODEL 1024
#define N_HEAD  16
#define DH      64
#define INNER   2816

typedef __attribute__((ext_vector_type(8))) short bf16x8;
typedef __attribute__((ext_vector_type(4))) float f32x4;
typedef __attribute__((ext_vector_type(8))) unsigned short us8v;
typedef __attribute__((ext_vector_type(4))) unsigned short us4v;

union BF16x8U { bf16x8 v; uint32_t u[4]; };

__device__ __forceinline__ unsigned short f2bf(float x) {
    union { __hip_bfloat16 h; unsigned short u; } c;
    c.h = __float2bfloat16(x);
    return c.u;
}

__device__ __forceinline__ float bf2f(unsigned short u) {
    union { float f; uint32_t i; } c;
    c.i = ((uint32_t)u) << 16;
    return c.f;
}

// pack two f32 -> one u32 of 2 bf16 in a single VALU instruction (gfx950)
__device__ __forceinline__ uint32_t cvt_pk_bf16(float lo, float hi) {
    uint32_t r;
    asm("v_cvt_pk_bf16_f32 %0, %1, %2" : "=v"(r) : "v"(lo), "v"(hi));
    return r;
}

__device__ __forceinline__ float silu_f(float x) {
    return x / (1.f + __expf(-x));
}

// async global->LDS, 16B per lane; LDS dest = wave-uniform base + lane*16
__device__ __forceinline__ void gld16(const unsigned short* g, unsigned short* l) {
    __builtin_amdgcn_global_load_lds(
        (const __attribute__((address_space(1))) void*)g,
        (__attribute__((address_space(3))) void*)l, 16, 0, 0);
}

// ---------------------------------------------------------------------------
// fp32 -> bf16 elementwise convert (8 elems/thread)
// ---------------------------------------------------------------------------
__global__ __launch_bounds__(256) void cvt_bf16(
    const float* __restrict__ in, unsigned short* __restrict__ out) {
    const size_t i8 = ((size_t)blockIdx.x * 256 + threadIdx.x) * 8;
    float4 a = *reinterpret_cast<const float4*>(&in[i8]);
    float4 b = *reinterpret_cast<const float4*>(&in[i8 + 4]);
    us8v o;
    o[0] = f2bf(a.x); o[1] = f2bf(a.y); o[2] = f2bf(a.z); o[3] = f2bf(a.w);
    o[4] = f2bf(b.x); o[5] = f2bf(b.y); o[6] = f2bf(b.z); o[7] = f2bf(b.w);
    *reinterpret_cast<us8v*>(&out[i8]) = o;
}

// ---------------------------------------------------------------------------
// ALL four weight transposes in ONE dispatch (fp32 [K][N] -> bf16 [N][K]).
// Flat grid 3136 blocks, range-decoded:
//   [0,768)     Wqkv  K=1024 N=3072 (nx=48)
//   [768,1024)  Wo    K=1024 N=1024 (nx=16)
//   [1024,2432) Wup   K=1024 N=5632 (nx=88)
//   [2432,3136) Wdown K=2816 N=1024 (nx=16)
// ---------------------------------------------------------------------------
__global__ __launch_bounds__(256) void transpose_all(
    const float* __restrict__ Wqkv, const float* __restrict__ Wo,
    const float* __restrict__ Wup, const float* __restrict__ Wdown,
    unsigned short* __restrict__ WqkvT, unsigned short* __restrict__ WoT,
    unsigned short* __restrict__ WupT, unsigned short* __restrict__ WdownT) {
    const int b = blockIdx.x;
    const float* W;
    unsigned short* WT;
    int K, N, bx, nx;
    if (b < 768)       { W = Wqkv;  WT = WqkvT;  K = 1024; N = 3072; bx = b;        nx = 48; }
    else if (b < 1024) { W = Wo;    WT = WoT;    K = 1024; N = 1024; bx = b - 768;  nx = 16; }
    else if (b < 2432) { W = Wup;   WT = WupT;   K = 1024; N = 5632; bx = b - 1024; nx = 88; }
    else               { W = Wdown; WT = WdownT; K = 2816; N = 1024; bx = b - 2432; nx = 16; }
    const int n0 = (bx % nx) * 64;
    const int k0 = (bx / nx) * 64;

    __shared__ unsigned short T[64][65];
    const int t = threadIdx.x;
#pragma unroll
    for (int i = 0; i < 4; ++i) {
        const int id = i * 256 + t;
        const int r = id >> 4;
        const int c = (id & 15) * 4;
        float4 v = *reinterpret_cast<const float4*>(
            &W[(size_t)(k0 + r) * N + n0 + c]);
        T[c + 0][r] = f2bf(v.x);
        T[c + 1][r] = f2bf(v.y);
        T[c + 2][r] = f2bf(v.z);
        T[c + 3][r] = f2bf(v.w);
    }
    __syncthreads();
#pragma unroll
    for (int i = 0; i < 2; ++i) {
        const int id = i * 256 + t;
        const int n = id >> 3;
        const int c = (id & 7) * 8;
        us8v o;
#pragma unroll
        for (int j = 0; j < 8; ++j) o[j] = T[n][c + j];
        *reinterpret_cast<us8v*>(&WT[(size_t)(n0 + n) * K + k0 + c]) = o;
    }
}

// ---------------------------------------------------------------------------
// bf16 MFMA GEMM (m97 structure): C = A @ Bt^T over K columns starting at
// blockIdx.z*K (row stride lda). 128x128 tile, BK=64, 4 waves.
// ---------------------------------------------------------------------------
template<int OBF>
__global__ __launch_bounds__(256) void gemm_bf16(
    const unsigned short* __restrict__ A, const unsigned short* __restrict__ Bt,
    void* __restrict__ Cout, int M, int N, int K, int lda) {
    __shared__ unsigned short As[128 * 64];
    __shared__ unsigned short Bs[128 * 64];
    const int tid = threadIdx.x;
    const int lane = tid & 63;
    const int w = tid >> 6;
    const int l15 = lane & 15, lg = lane >> 4;
    const int wm = w >> 1, wn = w & 1;
    const int rowBase = blockIdx.y * 128;
    const int colBase = blockIdx.x * 128;
    const size_t koff = (size_t)blockIdx.z * K;

    const int srow = w * 32 + (lane >> 3);
    const int scol = (lane & 7) * 8;
    const unsigned short* Ag = &A[(size_t)(rowBase + srow) * lda + koff + scol];
    const unsigned short* Bg = &Bt[(size_t)(colBase + srow) * lda + koff + scol];

    f32x4 acc[4][4];
#pragma unroll
    for (int i = 0; i < 4; ++i)
#pragma unroll
        for (int j = 0; j < 4; ++j) acc[i][j] = (f32x4){0.f, 0.f, 0.f, 0.f};

    for (int k0 = 0; k0 < K; k0 += 64) {
#pragma unroll
        for (int j = 0; j < 4; ++j) {
            gld16(Ag + (size_t)j * 8 * lda + k0, &As[(w * 32 + j * 8) * 64]);
            gld16(Bg + (size_t)j * 8 * lda + k0, &Bs[(w * 32 + j * 8) * 64]);
        }
        __syncthreads();
        bf16x8 af[2][4], bfr[2][4];
#pragma unroll
        for (int kk = 0; kk < 2; ++kk) {
#pragma unroll
            for (int f = 0; f < 4; ++f) {
                af[kk][f] = *reinterpret_cast<const bf16x8*>(
                    &As[(wm * 64 + f * 16 + l15) * 64 + kk * 32 + lg * 8]);
                bfr[kk][f] = *reinterpret_cast<const bf16x8*>(
                    &Bs[(wn * 64 + f * 16 + l15) * 64 + kk * 32 + lg * 8]);
            }
        }
#pragma unroll
        for (int kk = 0; kk < 2; ++kk)
#pragma unroll
            for (int mf = 0; mf < 4; ++mf)
#pragma unroll
                for (int nf = 0; nf < 4; ++nf)
                    acc[mf][nf] = __builtin_amdgcn_mfma_f32_16x16x32_bf16(
                        bfr[kk][nf], af[kk][mf], acc[mf][nf], 0, 0, 0);
        __syncthreads();
    }
#pragma unroll
    for (int mf = 0; mf < 4; ++mf) {
#pragma unroll
        for (int nf = 0; nf < 4; ++nf) {
            const size_t m = rowBase + wm * 64 + mf * 16 + l15;
            const size_t n = colBase + wn * 64 + nf * 16 + lg * 4;
            if (OBF) {
                us4v o;
                o[0] = f2bf(acc[mf][nf][0]); o[1] = f2bf(acc[mf][nf][1]);
                o[2] = f2bf(acc[mf][nf][2]); o[3] = f2bf(acc[mf][nf][3]);
                *reinterpret_cast<us4v*>(
                    &((unsigned short*)Cout)[(size_t)blockIdx.z * M * N + m * N + n]) = o;
            } else {
                float4 o;
                o.x = acc[mf][nf][0]; o.y = acc[mf][nf][1];
                o.z = acc[mf][nf][2]; o.w = acc[mf][nf][3];
                *reinterpret_cast<float4*>(
                    &((float*)Cout)[(size_t)blockIdx.z * M * N + m * N + n]) = o;
            }
        }
    }
}

// ---------------------------------------------------------------------------
// bf16 MFMA GEMM, 64x128 tile (for small-N GEMMs: 2 blocks/CU).
// ---------------------------------------------------------------------------
template<int OBF>
__global__ __launch_bounds__(256) void gemm_bf16_t64(
    const unsigned short* __restrict__ A, const unsigned short* __restrict__ Bt,
    void* __restrict__ Cout, int M, int N, int K) {
    __shared__ unsigned short As[64 * 64];
    __shared__ unsigned short Bs[128 * 64];
    const int tid = threadIdx.x;
    const int lane = tid & 63;
    const int w = tid >> 6;
    const int l15 = lane & 15, lg = lane >> 4;
    const int rowBase = blockIdx.y * 64;
    const int colBase = blockIdx.x * 128;

    const int srowA = w * 16 + (lane >> 3);
    const int srowB = w * 32 + (lane >> 3);
    const int scol = (lane & 7) * 8;
    const unsigned short* Ag = &A[(size_t)(rowBase + srowA) * K + scol];
    const unsigned short* Bg = &Bt[(size_t)(colBase + srowB) * K + scol];

    f32x4 acc[4][2];
#pragma unroll
    for (int i = 0; i < 4; ++i)
#pragma unroll
        for (int j = 0; j < 2; ++j) acc[i][j] = (f32x4){0.f, 0.f, 0.f, 0.f};

    for (int k0 = 0; k0 < K; k0 += 64) {
#pragma unroll
        for (int j = 0; j < 2; ++j)
            gld16(Ag + (size_t)j * 8 * K + k0, &As[(w * 16 + j * 8) * 64]);
#pragma unroll
        for (int j = 0; j < 4; ++j)
            gld16(Bg + (size_t)j * 8 * K + k0, &Bs[(w * 32 + j * 8) * 64]);
        __syncthreads();
        bf16x8 af[2][4], bfr[2][2];
#pragma unroll
        for (int kk = 0; kk < 2; ++kk) {
#pragma unroll
            for (int f = 0; f < 4; ++f)
                af[kk][f] = *reinterpret_cast<const bf16x8*>(
                    &As[(f * 16 + l15) * 64 + kk * 32 + lg * 8]);
#pragma unroll
            for (int f = 0; f < 2; ++f)
                bfr[kk][f] = *reinterpret_cast<const bf16x8*>(
                    &Bs[(w * 32 + f * 16 + l15) * 64 + kk * 32 + lg * 8]);
        }
#pragma unroll
        for (int kk = 0; kk < 2; ++kk)
#pragma unroll
            for (int mf = 0; mf < 4; ++mf)
#pragma unroll
                for (int nf = 0; nf < 2; ++nf)
                    acc[mf][nf] = __builtin_amdgcn_mfma_f32_16x16x32_bf16(
                        bfr[kk][nf], af[kk][mf], acc[mf][nf], 0, 0, 0);
        __syncthreads();
    }
#pragma unroll
    for (int mf = 0; mf < 4; ++mf) {
#pragma unroll
        for (int nf = 0; nf < 2; ++nf) {
            const size_t m = rowBase + mf * 16 + l15;
            const size_t n = colBase + w * 32 + nf * 16 + lg * 4;
            if (OBF) {
                us4v o;
                o[0] = f2bf(acc[mf][nf][0]); o[1] = f2bf(acc[mf][nf][1]);
                o[2] = f2bf(acc[mf][nf][2]); o[3] = f2bf(acc[mf][nf][3]);
                *reinterpret_cast<us4v*>(
                    &((unsigned short*)Cout)[m * N + n]) = o;
            } else {
                float4 o;
                o.x = acc[mf][nf][0]; o.y = acc[mf][nf][1];
                o.z = acc[mf][nf][2]; o.w = acc[mf][nf][3];
                *reinterpret_cast<float4*>(&((float*)Cout)[m * N + n]) = o;
            }
        }
    }
}

// ---------------------------------------------------------------------------
// RoPE + RMS-norm from bf16 qkv; emits Qb (PRE-SCALED by 1/8), Kb, Vt.
// (Vb eliminated: attn reads V straight from qkv_bf.)
// ---------------------------------------------------------------------------
__global__ __launch_bounds__(256) void rope_norm2(
    const unsigned short* __restrict__ qkv, const float* __restrict__ cosb,
    const float* __restrict__ sinb, unsigned short* __restrict__ Qb,
    unsigned short* __restrict__ Kb, unsigned short* __restrict__ Vt) {
    const int h = blockIdx.y;
    const int n0 = blockIdx.x * 64;
    const int wv = threadIdx.x >> 6;
    const int lane = threadIdx.x & 63;
    __shared__ unsigned short Vs[64][66];
#pragma unroll 1
    for (int it = 0; it < 16; ++it) {
        const int tn = it * 4 + wv;
        const int n = n0 + tn;
        const unsigned short* base = qkv + (size_t)n * (3 * D_MODEL) + h * DH;
        float qv = bf2f(base[lane]);
        float kv = bf2f(base[D_MODEL + lane]);
        const float c = cosb[n * DH + lane];
        const float s = sinb[n * DH + lane];
        const float qp = __shfl(qv, lane ^ 32, 64);
        const float kp = __shfl(kv, lane ^ 32, 64);
        const float sgn = (lane < 32) ? -1.f : 1.f;
        qv = qv * c + sgn * qp * s;
        kv = kv * c + sgn * kp * s;
        float sq = qv * qv, sk = kv * kv;
#pragma unroll
        for (int off = 32; off > 0; off >>= 1) {
            sq += __shfl_xor(sq, off, 64);
            sk += __shfl_xor(sk, off, 64);
        }
        qv *= rsqrtf(sq * (1.f / DH) + 1e-5f) * 0.125f;  // fold dh^-0.5 into Q
        kv *= rsqrtf(sk * (1.f / DH) + 1e-5f);
        const size_t o = ((size_t)h * N_TOK + n) * DH + lane;
        Qb[o] = f2bf(qv);
        Kb[o] = f2bf(kv);
        Vs[tn][lane] = base[2 * D_MODEL + lane];
    }
    __syncthreads();
    const int d = threadIdx.x >> 2;
    const int c0 = (threadIdx.x & 3) * 16;
    us8v o0, o1;
#pragma unroll
    for (int i = 0; i < 8; ++i) o0[i] = Vs[c0 + i][d];
#pragma unroll
    for (int i = 0; i < 8; ++i) o1[i] = Vs[c0 + 8 + i][d];
    unsigned short* dst = Vt + ((size_t)h * DH + d) * N_TOK + n0 + c0;
    *reinterpret_cast<us8v*>(dst) = o0;
    *reinterpret_cast<us8v*>(dst + 8) = o1;
}

// ---------------------------------------------------------------------------
// MFMA linear attention (R8-exact structure + cvt_pk pack — 153.6 us
// measured). V for the epilogue read directly from qkv_bf (Vb eliminated).
// ---------------------------------------------------------------------------
__global__ __launch_bounds__(256, 2) void attn_mfma2(
    const unsigned short* __restrict__ Qb, const unsigned short* __restrict__ Kb,
    const unsigned short* __restrict__ Vt, const unsigned short* __restrict__ qkv,
    unsigned short* __restrict__ Mout) {
    const int B = blockIdx.x;
    const int h = ((B & 7) << 1) | ((B >> 3) & 1);   // 2 heads per XCD
    const int q0 = (B >> 4) * 64;
    const int lane = threadIdx.x & 63;
    const int wv = threadIdx.x >> 6;
    const int l15 = lane & 15, lg = lane >> 4;
    const unsigned short* Qh = Qb + (size_t)h * N_TOK * DH;
    const unsigned short* Kh = Kb + (size_t)h * N_TOK * DH;
    const unsigned short* Vth = Vt + (size_t)h * DH * N_TOK;

    bf16x8 qf[4][2];
#pragma unroll
    for (int qs = 0; qs < 4; ++qs) {
        const unsigned short* qp = Qh + (size_t)(q0 + qs * 16 + l15) * DH + lg * 8;
        qf[qs][0] = *reinterpret_cast<const bf16x8*>(qp);
        qf[qs][1] = *reinterpret_cast<const bf16x8*>(qp + 32);
    }

    f32x4 ct[4][4];   // [qsub][ds]
#pragma unroll
    for (int i = 0; i < 4; ++i)
#pragma unroll
        for (int j = 0; j < 4; ++j) ct[i][j] = (f32x4){0.f, 0.f, 0.f, 0.f};
    float dpart[4] = {0.f, 0.f, 0.f, 0.f};

    const int sA = l15 + ((lg & 1) << 5);
    const int sB = sA + 16;
    const bool hi = (lg & 2) != 0;

#pragma unroll 1
    for (int kt = 0; kt < 16; ++kt) {
        const int k0 = (wv * 16 + kt) * 64;
        const unsigned short* kp = Kh + (size_t)(k0 + l15) * DH + lg * 8;
        bf16x8 kf[4][2];
#pragma unroll
        for (int ks = 0; ks < 4; ++ks) {
            kf[ks][0] = *reinterpret_cast<const bf16x8*>(kp + ks * 16 * DH);
            kf[ks][1] = *reinterpret_cast<const bf16x8*>(kp + ks * 16 * DH + 32);
        }
        const unsigned short* vp = Vth + (size_t)l15 * N_TOK + k0 + lg * 8;
        bf16x8 vf[4][2];
#pragma unroll
        for (int ds = 0; ds < 4; ++ds) {
            vf[ds][0] = *reinterpret_cast<const bf16x8*>(vp + (size_t)ds * 16 * N_TOK);
            vf[ds][1] = *reinterpret_cast<const bf16x8*>(vp + (size_t)ds * 16 * N_TOK + 32);
        }
#pragma unroll
        for (int qs = 0; qs < 4; ++qs) {
            // S^T subtiles (Q pre-scaled by 1/8)
            f32x4 st[4];
            __builtin_amdgcn_s_setprio(1);
#pragma unroll
            for (int ks = 0; ks < 4; ++ks) {
                f32x4 z = (f32x4){0.f, 0.f, 0.f, 0.f};
                z = __builtin_amdgcn_mfma_f32_16x16x32_bf16(kf[ks][0], qf[qs][0], z, 0, 0, 0);
                st[ks] = __builtin_amdgcn_mfma_f32_16x16x32_bf16(kf[ks][1], qf[qs][1], z, 0, 0, 0);
            }
            __builtin_amdgcn_s_setprio(0);
            // W = (elu(s)+1)^2, per-lane denom partial, pack via v_cvt_pk
            uint32_t wpk[4][2];
#pragma unroll
            for (int ks = 0; ks < 4; ++ks) {
                float w4[4];
#pragma unroll
                for (int r = 0; r < 4; ++r) {
                    const float x = st[ks][r];
                    float e = fmaxf(x, 0.f) + __expf(fminf(x, 0.f));
                    e = e * e;
                    w4[r] = e;
                    dpart[qs] += e;
                }
                wpk[ks][0] = cvt_pk_bf16(w4[0], w4[1]);
                wpk[ks][1] = cvt_pk_bf16(w4[2], w4[3]);
            }
            // repack W^T C-frags -> PV B-operand (16 shfls)
#pragma unroll
            for (int kh = 0; kh < 2; ++kh) {
                const uint32_t a0 = (uint32_t)__shfl((int)wpk[2 * kh][0], sA, 64);
                const uint32_t a1 = (uint32_t)__shfl((int)wpk[2 * kh][1], sA, 64);
                const uint32_t a2 = (uint32_t)__shfl((int)wpk[2 * kh][0], sB, 64);
                const uint32_t a3 = (uint32_t)__shfl((int)wpk[2 * kh][1], sB, 64);
                const uint32_t b0 = (uint32_t)__shfl((int)wpk[2 * kh + 1][0], sA, 64);
                const uint32_t b1 = (uint32_t)__shfl((int)wpk[2 * kh + 1][1], sA, 64);
                const uint32_t b2 = (uint32_t)__shfl((int)wpk[2 * kh + 1][0], sB, 64);
                const uint32_t b3 = (uint32_t)__shfl((int)wpk[2 * kh + 1][1], sB, 64);
                BF16x8U bb;
                bb.u[0] = hi ? b0 : a0;
                bb.u[1] = hi ? b1 : a1;
                bb.u[2] = hi ? b2 : a2;
                bb.u[3] = hi ? b3 : a3;
                __builtin_amdgcn_s_setprio(1);
#pragma unroll
                for (int ds = 0; ds < 4; ++ds)
                    ct[qs][ds] = __builtin_amdgcn_mfma_f32_16x16x32_bf16(
                        vf[ds][kh], bb.v, ct[qs][ds], 0, 0, 0);
                __builtin_amdgcn_s_setprio(0);
            }
        }
    }

    // ---- two-phase cross-wave reduction ----
    __shared__ float accs2[2][64][72];   // 36,864 B
    __shared__ float dens[4][64];        //  1,024 B
#pragma unroll
    for (int qs = 0; qs < 4; ++qs) {
        float dp = dpart[qs];
        dp += __shfl_xor(dp, 16, 64);
        dp += __shfl_xor(dp, 32, 64);
        if (lg == 0) dens[wv][qs * 16 + l15] = dp;
    }
    if (wv >= 2) {
#pragma unroll
        for (int qs = 0; qs < 4; ++qs)
#pragma unroll
            for (int ds = 0; ds < 4; ++ds)
                *reinterpret_cast<f32x4*>(
                    &accs2[wv - 2][qs * 16 + l15][ds * 16 + lg * 4]) = ct[qs][ds];
    }
    __syncthreads();
    if (wv < 2) {
#pragma unroll
        for (int qs = 0; qs < 4; ++qs)
#pragma unroll
            for (int ds = 0; ds < 4; ++ds)
                ct[qs][ds] += *reinterpret_cast<const f32x4*>(
                    &accs2[wv][qs * 16 + l15][ds * 16 + lg * 4]);
        if (wv == 1) {
#pragma unroll
            for (int qs = 0; qs < 4; ++qs)
#pragma unroll
                for (int ds = 0; ds < 4; ++ds)
                    *reinterpret_cast<f32x4*>(
                        &accs2[1][qs * 16 + l15][ds * 16 + lg * 4]) = ct[qs][ds];
        }
    }
    __syncthreads();
    if (wv == 0) {
#pragma unroll
        for (int qs = 0; qs < 4; ++qs) {
            const int q = qs * 16 + l15;
            const float dnq = 1.f /
                (dens[0][q] + dens[1][q] + dens[2][q] + dens[3][q] + 1e-6f);
            // V read directly from qkv_bf [n][3*D_MODEL] layout
            const unsigned short* Vrow =
                qkv + (size_t)(q0 + q) * (3 * D_MODEL) + 2 * D_MODEL + h * DH;
            unsigned short* Mrow = Mout + (size_t)(q0 + q) * D_MODEL + h * DH;
#pragma unroll
            for (int ds = 0; ds < 4; ++ds) {
                const int d = ds * 16 + lg * 4;
                const f32x4 s1 = *reinterpret_cast<const f32x4*>(&accs2[1][q][d]);
                const us4v vv = *reinterpret_cast<const us4v*>(&Vrow[d]);
                us4v o;
#pragma unroll
                for (int r = 0; r < 4; ++r)
                    o[r] = f2bf((ct[qs][ds][r] + s1[r]) * dnq - bf2f(vv[r]));
                *reinterpret_cast<us4v*>(&Mrow[d]) = o;
            }
        }
    }
}

// ---------------------------------------------------------------------------
// O = rmsnorm(X + R); fp32 out always, bf16 out if WB.
// ---------------------------------------------------------------------------
template<int WB>
__global__ __launch_bounds__(256) void rms_resid2(
    const float* __restrict__ X, const float* __restrict__ R,
    float* __restrict__ O32, unsigned short* __restrict__ Obf) {
    const int row = blockIdx.x;
    const int tid = threadIdx.x;
    const float4 xv = reinterpret_cast<const float4*>(X + (size_t)row * D_MODEL)[tid];
    const float4 rv = reinterpret_cast<const float4*>(R + (size_t)row * D_MODEL)[tid];
    const float t0 = xv.x + rv.x, t1 = xv.y + rv.y, t2 = xv.z + rv.z, t3 = xv.w + rv.w;
    float ss = t0 * t0 + t1 * t1 + t2 * t2 + t3 * t3;
#pragma unroll
    for (int off = 32; off > 0; off >>= 1) ss += __shfl_xor(ss, off, 64);
    __shared__ float red[4];
    if ((tid & 63) == 0) red[tid >> 6] = ss;
    __syncthreads();
    const float tot = red[0] + red[1] + red[2] + red[3];
    const float rs = rsqrtf(tot * (1.f / D_MODEL) + 1e-5f);
    float4 o;
    o.x = t0 * rs; o.y = t1 * rs; o.z = t2 * rs; o.w = t3 * rs;
    reinterpret_cast<float4*>(O32 + (size_t)row * D_MODEL)[tid] = o;
    if (WB) {
        us4v ob;
        ob[0] = f2bf(o.x); ob[1] = f2bf(o.y); ob[2] = f2bf(o.z); ob[3] = f2bf(o.w);
        *reinterpret_cast<us4v*>(&Obf[(size_t)row * D_MODEL + tid * 4]) = ob;
    }
}

// O = rmsnorm(Xa + Xb + R)  (split-K partial sum folded in; fp32 out)
__global__ __launch_bounds__(256) void rms_resid3(
    const float* __restrict__ Xa, const float* __restrict__ Xb,
    const float* __restrict__ R, float* __restrict__ O32) {
    const int row = blockIdx.x;
    const int tid = threadIdx.x;
    const float4 av = reinterpret_cast<const float4*>(Xa + (size_t)row * D_MODEL)[tid];
    const float4 bv = reinterpret_cast<const float4*>(Xb + (size_t)row * D_MODEL)[tid];
    const float4 rv = reinterpret_cast<const float4*>(R + (size_t)row * D_MODEL)[tid];
    const float t0 = av.x + bv.x + rv.x, t1 = av.y + bv.y + rv.y;
    const float t2 = av.z + bv.z + rv.z, t3 = av.w + bv.w + rv.w;
    float ss = t0 * t0 + t1 * t1 + t2 * t2 + t3 * t3;
#pragma unroll
    for (int off = 32; off > 0; off >>= 1) ss += __shfl_xor(ss, off, 64);
    __shared__ float red[4];
    if ((tid & 63) == 0) red[tid >> 6] = ss;
    __syncthreads();
    const float tot = red[0] + red[1] + red[2] + red[3];
    const float rs = rsqrtf(tot * (1.f / D_MODEL) + 1e-5f);
    float4 o;
    o.x = t0 * rs; o.y = t1 * rs; o.z = t2 * rs; o.w = t3 * rs;
    reinterpret_cast<float4*>(O32 + (size_t)row * D_MODEL)[tid] = o;
}

// ---------------------------------------------------------------------------
// FUSED: Hc = silu(conv3(silu(G)*U) + bias); reads GU directly.
// ---------------------------------------------------------------------------
__global__ __launch_bounds__(256) void dwconv_fused(
    const unsigned short* __restrict__ GU, const float* __restrict__ W,
    const float* __restrict__ Bv, unsigned short* __restrict__ Hc) {
    const size_t idx = (size_t)blockIdx.x * 256 + threadIdx.x;
    const int c8 = (int)(idx % (INNER / 8)) * 8;
    const int n = (int)(idx / (INNER / 8));
    float a[8];
    {
        float4 b0 = *reinterpret_cast<const float4*>(&Bv[c8]);
        float4 b1 = *reinterpret_cast<const float4*>(&Bv[c8 + 4]);
        a[0] = b0.x; a[1] = b0.y; a[2] = b0.z; a[3] = b0.w;
        a[4] = b1.x; a[5] = b1.y; a[6] = b1.z; a[7] = b1.w;
    }
#pragma unroll
    for (int k = 0; k < 3; ++k) {
        const int nn = n + k - 1;
        if (nn >= 0 && nn < N_TOK) {
            const unsigned short* row = &GU[(size_t)nn * (2 * INNER)];
            us8v g = *reinterpret_cast<const us8v*>(&row[c8]);
            us8v u = *reinterpret_cast<const us8v*>(&row[INNER + c8]);
            float4 w0 = *reinterpret_cast<const float4*>(&W[(size_t)k * INNER + c8]);
            float4 w1 = *reinterpret_cast<const float4*>(&W[(size_t)k * INNER + c8 + 4]);
            const float wv[8] = {w0.x, w0.y, w0.z, w0.w, w1.x, w1.y, w1.z, w1.w};
#pragma unroll
            for (int j = 0; j < 8; ++j) {
                const float hf = silu_f(bf2f(g[j])) * bf2f(u[j]);
                a[j] += hf * wv[j];
            }
        }
    }
    us8v o;
#pragma unroll
    for (int j = 0; j < 8; ++j) o[j] = f2bf(silu_f(a[j]));
    *reinterpret_cast<us8v*>(&Hc[(size_t)n * INNER + c8]) = o;
}

extern "C" void kernel_launch(void* const* d_in, const int* in_sizes, int n_in,
                              void* d_out, int out_size, void* d_ws, size_t ws_size,
                              hipStream_t stream) {
    const float* Qin   = (const float*)d_in[0];
    const float* cosb  = (const float*)d_in[1];
    const float* sinb  = (const float*)d_in[2];
    const float* Wqkv  = (const float*)d_in[3];
    const float* Wo    = (const float*)d_in[4];
    const float* Wup   = (const float*)d_in[5];
    const float* convw = (const float*)d_in[6];
    const float* convb = (const float*)d_in[7];
    const float* Wdown = (const float*)d_in[8];
    float* out = (float*)d_out;
    float* ws  = (float*)d_ws;

    // ---- workspace layout (float-unit offsets; peak ~139 MB)
    unsigned short* WqkvT  = (unsigned short*)(ws);              // [3072][1024]
    unsigned short* WoT    = (unsigned short*)(ws + 1572864);    // [1024][1024]
    unsigned short* WupT   = (unsigned short*)(ws + 2097152);    // [5632][1024]
    unsigned short* WdownT = (unsigned short*)(ws + 4980736);    // [1024][2816]
    unsigned short* Qin_bf = (unsigned short*)(ws + 6422528);    // [4096][1024]
    unsigned short* mcat   = (unsigned short*)(ws + 6422528);    // reuse (after QKV GEMM)
    unsigned short* qkv_bf = (unsigned short*)(ws + 8519680);    // [4096][3072] bf16 (live thru attn)
    float*          wo32   = ws + 8519680;                       // reuse (after attn)
    unsigned short* GU     = (unsigned short*)(ws + 8519680);    // [4096][5632] (after rms5)
    float*          dn32   = ws + 8519680;                       // [2][4096][1024] (after conv)
    unsigned short* Qb     = (unsigned short*)(ws + 21102592);
    unsigned short* Kb     = (unsigned short*)(ws + 23199744);
    unsigned short* Vt     = (unsigned short*)(ws + 25296896);
    unsigned short* Hc     = (unsigned short*)(ws + 21102592);   // [4096][2816] (after attn)
    float*          Qi32   = ws + 29491200;                      // [4096][1024]
    unsigned short* Qi_bf  = (unsigned short*)(ws + 33685504);   // [4096][1024]

    const dim3 blk(256);
    // 0. weight / input prep (2 dispatches)
    cvt_bf16<<<2048, blk, 0, stream>>>(Qin, Qin_bf);
    transpose_all<<<3136, blk, 0, stream>>>(
        Wqkv, Wo, Wup, Wdown, WqkvT, WoT, WupT, WdownT);
    // 1. QKV projection (bf16 out — RoPE/RMS read bf16)
    gemm_bf16<1><<<dim3(24, 32), blk, 0, stream>>>(
        Qin_bf, WqkvT, qkv_bf, 4096, 3072, 1024, 1024);
    // 2. RoPE + RMS + transposes (Vb eliminated)
    rope_norm2<<<dim3(64, 16), blk, 0, stream>>>(qkv_bf, cosb, sinb, Qb, Kb, Vt);
    // 3. attention -> m_concat (bf16); V read from qkv_bf
    attn_mfma2<<<1024, blk, 0, stream>>>(Qb, Kb, Vt, qkv_bf, mcat);
    // 4. W_o projection (fp32 out) — 64x128 tile: 512 blocks = 2/CU
    gemm_bf16_t64<0><<<dim3(8, 64), blk, 0, stream>>>(
        mcat, WoT, wo32, 4096, 1024, 1024);
    // 5. Q_interact = rmsnorm(Q_in + wo_out) -> fp32 + bf16
    rms_resid2<1><<<4096, blk, 0, stream>>>(wo32, Qin, Qi32, Qi_bf);
    // 6. GU = Qi @ Wup (bf16 out)
    gemm_bf16<1><<<dim3(44, 32), blk, 0, stream>>>(
        Qi_bf, WupT, GU, 4096, 5632, 1024, 1024);
    // 7+8. fused silu-mul + depthwise conv + bias + silu -> Hc
    dwconv_fused<<<5632, blk, 0, stream>>>(GU, convw, convb, Hc);
    // 9. W_down projection, split-K=2 (128x128 tile, 512 blocks = 2/CU)
    gemm_bf16<0><<<dim3(8, 32, 2), blk, 0, stream>>>(
        Hc, WdownT, dn32, 4096, 1024, 1408, 2816);
    // 10. out = rmsnorm(Qi + dnA + dnB)
    rms_resid3<<<4096, blk, 0, stream>>>(dn32, dn32 + 4194304, Qi32, out);
}